// Round 7
// baseline (1253.532 us; speedup 1.0000x reference)
//
#include <hip/hip_runtime.h>
#include <stdint.h>

#define NN 50000
#define H 150
#define NE 400000
#define NG 64
#define NPASS 5
#define KB 480          // GRU GEMM K: [S0(160) | S1(160) | nodes(160)]
#define VC 640          // 40 col-tiles: v = cc*64 + g*16 + cl, c = cc*16+cl
#define NRB 391         // row blocks of 128

typedef unsigned short u16;
typedef unsigned int u32;
typedef __attribute__((ext_vector_type(8))) short short8;
typedef __attribute__((ext_vector_type(4))) float float4v;

// ---------------- helpers ----------------
__device__ __forceinline__ u16 f2bf_rn(float x) {
  union { float f; u32 u; } v; v.f = x;
  u32 r = v.u + 0x7fffu + ((v.u >> 16) & 1u);
  return (u16)(r >> 16);
}
__device__ __forceinline__ float bf2f(u16 h) {
  union { u32 u; float f; } v; v.u = ((u32)h) << 16;
  return v.f;
}
// packed word: low16 = hi bf16, high16 = lo bf16; value = hi + lo
__device__ __forceinline__ u32 packf(float v) {
  u16 hi = f2bf_rn(v);
  u16 lo = f2bf_rn(v - bf2f(hi));
  return (u32)hi | ((u32)lo << 16);
}
// async global->LDS, 16B per lane; lds dest must be wave-uniform base
__device__ __forceinline__ void async16(const void* g, void* l) {
  __builtin_amdgcn_global_load_lds(
      (const __attribute__((address_space(1))) unsigned int*)(uintptr_t)g,
      (__attribute__((address_space(3))) unsigned int*)(uint32_t)(uintptr_t)l,
      16, 0, 0);
}

// ---------------- CSR build (key = node*2 + set) ----------------
__global__ void hist_kernel(const int* __restrict__ edges, int* __restrict__ cnt) {
  int id = blockIdx.x * 256 + threadIdx.x;
  if (id >= 2 * NE) return;
  int dst = edges[id * 2];
  int set = id / NE;
  atomicAdd(&cnt[dst * 2 + set], 1);
}

__global__ __launch_bounds__(1024) void scan1_kernel(const int* __restrict__ cnt,
                                                     int* __restrict__ rowptr,
                                                     int* __restrict__ bsum, int n) {
  __shared__ int sd[1024];
  int t = threadIdx.x;
  int idx = blockIdx.x * 1024 + t;
  int v = (idx < n) ? cnt[idx] : 0;
  sd[t] = v;
  __syncthreads();
  for (int off = 1; off < 1024; off <<= 1) {
    int add = (t >= off) ? sd[t - off] : 0;
    __syncthreads();
    sd[t] += add;
    __syncthreads();
  }
  if (idx < n) rowptr[idx] = sd[t] - v;     // block-local exclusive
  if (t == 1023) bsum[blockIdx.x] = sd[1023];
}

__global__ __launch_bounds__(128) void scan2_kernel(const int* __restrict__ bsum,
                                                    int* __restrict__ boff, int nb) {
  __shared__ int sd[128];
  int t = threadIdx.x;
  int v = (t < nb) ? bsum[t] : 0;
  sd[t] = v;
  __syncthreads();
  for (int off = 1; off < 128; off <<= 1) {
    int add = (t >= off) ? sd[t - off] : 0;
    __syncthreads();
    sd[t] += add;
    __syncthreads();
  }
  boff[t] = sd[t] - v;                       // exclusive; boff[nb] = total
}

__global__ void scan3_kernel(int* __restrict__ rowptr, const int* __restrict__ boff, int n) {
  int idx = blockIdx.x * 256 + threadIdx.x;
  if (idx < n) rowptr[idx] += boff[idx >> 10];
}

__global__ void total_kernel(int* __restrict__ rowptr, const int* __restrict__ boff, int n, int nb) {
  if (threadIdx.x == 0 && blockIdx.x == 0) rowptr[n] = boff[nb];
}

__global__ void copy_int_kernel(const int* __restrict__ a, int* __restrict__ b, int n) {
  int id = blockIdx.x * 256 + threadIdx.x;
  if (id < n) b[id] = a[id];
}

__global__ void fill_kernel(const int* __restrict__ edges, int* __restrict__ cursor,
                            u16* __restrict__ colbuf) {
  int id = blockIdx.x * 256 + threadIdx.x;
  if (id >= 2 * NE) return;
  int dst = edges[id * 2];
  int src = edges[id * 2 + 1];
  int set = id / NE;
  int pos = atomicAdd(&cursor[dst * 2 + set], 1);
  colbuf[pos] = (u16)src;
}

__global__ void bounds_kernel(const int* __restrict__ gids, int* __restrict__ gstart) {
  int g = threadIdx.x;
  if (g > NG) return;
  int lo = 0, hi = NN;
  while (lo < hi) { int m = (lo + hi) >> 1; if (gids[m] < g) lo = m + 1; else hi = m; }
  gstart[g] = lo;
}

// ---------------- one-time weight prep ----------------
// B'[v][k], v in [0,640): g=(v>>4)&3, c=(v>>6)*16+(v&15)
// k<160: (W_ihg @ W0)[c][k]      (g<3; g3=0)
// 160<=k<320: (W_ihg @ W1)[c][k-160]
// 320<=k<480: g0: w_hh[c][kk], g1: w_hh[150+c][kk], g3: w_hh[300+c][kk], g2: 0
__global__ void build_B_kernel(const float* __restrict__ wih, const float* __restrict__ whh,
                               const float* __restrict__ eW,
                               u16* __restrict__ Bh, u16* __restrict__ Bl) {
  int id = blockIdx.x * 256 + threadIdx.x;
  if (id >= VC * KB) return;
  int v = id / KB, k = id % KB;
  int g = (v >> 4) & 3, c = (v >> 6) * 16 + (v & 15);
  int seg = k / 160, kk = k % 160;
  float val = 0.f;
  if (c < H && kk < H) {
    if (seg < 2) {
      if (g < 3) {
        const float* wr = wih + (size_t)(g * H + c) * H;
        const float* wc = eW + (size_t)seg * H * H + kk;
        float acc = 0.f;
        for (int t = 0; t < H; t++) acc += wr[t] * wc[(size_t)t * H];
        val = acc;
      }
    } else {
      if (g == 0) val = whh[(size_t)c * H + kk];
      else if (g == 1) val = whh[(size_t)(H + c) * H + kk];
      else if (g == 3) val = whh[(size_t)(2 * H + c) * H + kk];
    }
  }
  u16 h = f2bf_rn(val);
  Bh[id] = h;
  Bl[id] = f2bf_rn(val - bf2f(h));
}

// coefs[0][g*160+c] = W_ihg @ b0 (deg0 coef), coefs[1] = W_ihg @ b1, coefs[2] = gate bias
__global__ void build_coef_kernel(const float* __restrict__ wih,
                                  const float* __restrict__ eb,
                                  const float* __restrict__ bih, const float* __restrict__ bhh,
                                  float* __restrict__ coefs) {
  int id = threadIdx.x + blockIdx.x * 256;
  if (id >= VC) return;
  int g = id / 160, c = id % 160;
  float u0 = 0.f, u1 = 0.f, bs = 0.f;
  if (c < H) {
    if (g < 3) {
      const float* wr = wih + (size_t)(g * H + c) * H;
      for (int t = 0; t < H; t++) { u0 += wr[t] * eb[t]; u1 += wr[t] * eb[H + t]; }
    }
    if (g == 0) bs = bih[c] + bhh[c];
    else if (g == 1) bs = bih[H + c] + bhh[H + c];
    else if (g == 2) bs = bih[2 * H + c];
    else bs = bhh[2 * H + c];
  }
  coefs[id] = u0;
  coefs[VC + id] = u1;
  coefs[2 * VC + id] = bs;
}

// R17: node state lives as TWO bf16 planes (nh=hi, nl=lo). Init pass-A values,
// zero pad cols (150..159) of both buffer sets (GEMM stages full 160-col rows).
__global__ void init_nodes_kernel(const float* __restrict__ nin,
                                  u16* __restrict__ nhA, u16* __restrict__ nlA,
                                  u16* __restrict__ nhB, u16* __restrict__ nlB) {
  int id = blockIdx.x * 256 + threadIdx.x;
  if (id >= NN * 160) return;
  int r = id / 160, c = id % 160;
  u32 pw = 0;
  if (c < H) pw = packf(nin[(size_t)r * H + c]);
  nhA[id] = (u16)pw;
  nlA[id] = (u16)(pw >> 16);
  if (c >= H) { nhB[id] = 0; nlB[id] = 0; }
}

// zero the pad columns of Sh/Sl (cols 150..159 per set) — gather never writes them
__global__ void pad_S_kernel(u16* __restrict__ Sh, u16* __restrict__ Sl) {
  int id = blockIdx.x * 256 + threadIdx.x;
  if (id >= NN * 20) return;
  int r = id / 20, rem = id % 20;
  int set = rem / 10, t = rem % 10;
  size_t off = (size_t)r * 320 + set * 160 + H + t;
  Sh[off] = 0; Sl[off] = 0;
}

// ---------------- gather: S[n][set*160+c] = sum of node rows (split planes) ----
// R17: reads nh/nl planes. Lane handles col pair (2l, 2l+1) via one u32 load per
// plane; tail cols 128..149 as pairs (128+2l) for lanes 0..10 — SAME instruction
// count as R14 (2.34 loads/edge). Per-column accumulation order identical
// ((x0+x1)+(x2+x3) pair grouping) -> bit-identical results.
__global__ __launch_bounds__(256) void gather_kernel(
    const u16* __restrict__ nh, const u16* __restrict__ nl,
    const int* __restrict__ rowptr, const u16* __restrict__ colbuf,
    u16* __restrict__ Sh, u16* __restrict__ Sl) {
  int gtid = blockIdx.x * 256 + threadIdx.x;
  int wid = gtid >> 6;
  if (wid >= 2 * NN) return;
  int node = wid >> 1, set = wid & 1;
  int lane = gtid & 63;
  int s = rowptr[2 * node + set], e = rowptr[2 * node + set + 1];
  int deg = e - s;
  int cA = 2 * lane, cC = 128 + 2 * lane;
  bool okC = (lane < 11);              // pairs (128,129)..(148,149)
  float aA = 0.f, aB = 0.f, aC = 0.f, aD = 0.f;
  for (int base = 0; base < deg; base += 64) {
    int rem = min(64, deg - base);
    u32 srcv = 0;
    if (lane < rem) srcv = (u32)colbuf[s + base + lane];
    int i = 0;
    for (; i + 3 < rem; i += 4) {
      int r0 = __builtin_amdgcn_readlane((int)srcv, i);
      int r1 = __builtin_amdgcn_readlane((int)srcv, i + 1);
      int r2 = __builtin_amdgcn_readlane((int)srcv, i + 2);
      int r3 = __builtin_amdgcn_readlane((int)srcv, i + 3);
      const u16* h0 = nh + (size_t)(u32)r0 * 160; const u16* L0 = nl + (size_t)(u32)r0 * 160;
      const u16* h1 = nh + (size_t)(u32)r1 * 160; const u16* L1 = nl + (size_t)(u32)r1 * 160;
      const u16* h2 = nh + (size_t)(u32)r2 * 160; const u16* L2 = nl + (size_t)(u32)r2 * 160;
      const u16* h3 = nh + (size_t)(u32)r3 * 160; const u16* L3 = nl + (size_t)(u32)r3 * 160;
      u32 vh0 = *(const u32*)(h0 + cA), vl0 = *(const u32*)(L0 + cA);
      u32 vh1 = *(const u32*)(h1 + cA), vl1 = *(const u32*)(L1 + cA);
      u32 vh2 = *(const u32*)(h2 + cA), vl2 = *(const u32*)(L2 + cA);
      u32 vh3 = *(const u32*)(h3 + cA), vl3 = *(const u32*)(L3 + cA);
      u32 wh0 = 0, wl0 = 0, wh1 = 0, wl1 = 0, wh2 = 0, wl2 = 0, wh3 = 0, wl3 = 0;
      if (okC) {
        wh0 = *(const u32*)(h0 + cC); wl0 = *(const u32*)(L0 + cC);
        wh1 = *(const u32*)(h1 + cC); wl1 = *(const u32*)(L1 + cC);
        wh2 = *(const u32*)(h2 + cC); wl2 = *(const u32*)(L2 + cC);
        wh3 = *(const u32*)(h3 + cC); wl3 = *(const u32*)(L3 + cC);
      }
      aA += (bf2f((u16)vh0) + bf2f((u16)vl0)) + (bf2f((u16)vh1) + bf2f((u16)vl1));
      aB += (bf2f((u16)(vh0 >> 16)) + bf2f((u16)(vl0 >> 16))) + (bf2f((u16)(vh1 >> 16)) + bf2f((u16)(vl1 >> 16)));
      if (okC) {
        aC += (bf2f((u16)wh0) + bf2f((u16)wl0)) + (bf2f((u16)wh1) + bf2f((u16)wl1));
        aD += (bf2f((u16)(wh0 >> 16)) + bf2f((u16)(wl0 >> 16))) + (bf2f((u16)(wh1 >> 16)) + bf2f((u16)(wl1 >> 16)));
      }
      aA += (bf2f((u16)vh2) + bf2f((u16)vl2)) + (bf2f((u16)vh3) + bf2f((u16)vl3));
      aB += (bf2f((u16)(vh2 >> 16)) + bf2f((u16)(vl2 >> 16))) + (bf2f((u16)(vh3 >> 16)) + bf2f((u16)(vl3 >> 16)));
      if (okC) {
        aC += (bf2f((u16)wh2) + bf2f((u16)wl2)) + (bf2f((u16)wh3) + bf2f((u16)wl3));
        aD += (bf2f((u16)(wh2 >> 16)) + bf2f((u16)(wl2 >> 16))) + (bf2f((u16)(wh3 >> 16)) + bf2f((u16)(wl3 >> 16)));
      }
    }
    for (; i + 1 < rem; i += 2) {
      int r0 = __builtin_amdgcn_readlane((int)srcv, i);
      int r1 = __builtin_amdgcn_readlane((int)srcv, i + 1);
      const u16* h0 = nh + (size_t)(u32)r0 * 160; const u16* L0 = nl + (size_t)(u32)r0 * 160;
      const u16* h1 = nh + (size_t)(u32)r1 * 160; const u16* L1 = nl + (size_t)(u32)r1 * 160;
      u32 vh0 = *(const u32*)(h0 + cA), vl0 = *(const u32*)(L0 + cA);
      u32 vh1 = *(const u32*)(h1 + cA), vl1 = *(const u32*)(L1 + cA);
      aA += (bf2f((u16)vh0) + bf2f((u16)vl0)) + (bf2f((u16)vh1) + bf2f((u16)vl1));
      aB += (bf2f((u16)(vh0 >> 16)) + bf2f((u16)(vl0 >> 16))) + (bf2f((u16)(vh1 >> 16)) + bf2f((u16)(vl1 >> 16)));
      if (okC) {
        u32 wh0 = *(const u32*)(h0 + cC), wl0 = *(const u32*)(L0 + cC);
        u32 wh1 = *(const u32*)(h1 + cC), wl1 = *(const u32*)(L1 + cC);
        aC += (bf2f((u16)wh0) + bf2f((u16)wl0)) + (bf2f((u16)wh1) + bf2f((u16)wl1));
        aD += (bf2f((u16)(wh0 >> 16)) + bf2f((u16)(wl0 >> 16))) + (bf2f((u16)(wh1 >> 16)) + bf2f((u16)(wl1 >> 16)));
      }
    }
    if (i < rem) {
      int r0 = __builtin_amdgcn_readlane((int)srcv, i);
      const u16* h0 = nh + (size_t)(u32)r0 * 160; const u16* L0 = nl + (size_t)(u32)r0 * 160;
      u32 vh0 = *(const u32*)(h0 + cA), vl0 = *(const u32*)(L0 + cA);
      aA += bf2f((u16)vh0) + bf2f((u16)vl0);
      aB += bf2f((u16)(vh0 >> 16)) + bf2f((u16)(vl0 >> 16));
      if (okC) {
        u32 wh0 = *(const u32*)(h0 + cC), wl0 = *(const u32*)(L0 + cC);
        aC += bf2f((u16)wh0) + bf2f((u16)wl0);
        aD += bf2f((u16)(wh0 >> 16)) + bf2f((u16)(wl0 >> 16));
      }
    }
  }
  u16* oh = Sh + (size_t)node * 320 + set * 160;
  u16* ol = Sl + (size_t)node * 320 + set * 160;
  u32 pA = packf(aA), pB = packf(aB);
  *(u32*)(oh + cA) = (pA & 0xffffu) | (pB << 16);
  *(u32*)(ol + cA) = (pA >> 16) | (pB & 0xffff0000u);
  if (okC) {
    u32 pC = packf(aC), pD = packf(aD);
    *(u32*)(oh + cC) = (pC & 0xffffu) | (pD << 16);
    *(u32*)(ol + cC) = (pC >> 16) | (pD & 0xffff0000u);
  }
}

// ---------------- fused GRU GEMM — R17: split hi/lo planes, zero unpack -------
// R16 schedule kept (single 32KB buffer set, 2-phase per kt, 4+ blocks/CU).
// A-tile now staged as two bf16 planes (64B rows, R12's 1.25M-conflict layout,
// 3x fewer conflicts than packed 128B rows) and frags are DIRECT short8
// ds_reads — the per-kt unpack VALU (~32-48 ops/wave) is gone entirely.
// All 15 kts share one stage/read shape; only the B gate-select differs.
// MFMA operand values and order unchanged -> bit-identical output.

template<int KT>
__device__ __forceinline__ void stage_fn(
    const u16* __restrict__ Shp, const u16* __restrict__ Slp,
    const u16* __restrict__ nhc, const u16* __restrict__ nlc,
    const u16* __restrict__ Bhp, const u16* __restrict__ Blp,
    char* Ab, char* Bb, int tid, int w, int r0, int ccb) {
  constexpr int koffB = (KT < 10) ? KT * 32 : 320 + (KT - 10) * 32;
  constexpr int skipg = (KT < 10) ? 3 : 2;      // zero-gate rows (exact skip)
  #pragma unroll
  for (int i = 0; i < 2; i++) {
    int cl = i * 256 + tid;                     // [0,512)
    int row = cl >> 2;
    int q = (cl & 3) ^ ((row >> 1) & 3);
    int rg = min(r0 + row, NN - 1);
    int lb = i * 4096 + w * 1024;
    if constexpr (KT < 10) {
      size_t go = (size_t)rg * 320 + KT * 32 + q * 8;
      async16(Shp + go, Ab + lb);
      async16(Slp + go, Ab + 8192 + lb);
    } else {
      size_t go = (size_t)rg * 160 + (KT - 10) * 32 + q * 8;
      async16(nhc + go, Ab + lb);
      async16(nlc + go, Ab + 8192 + lb);
    }
    if (((row >> 4) & 3) != skipg) {            // wave-uniform predicate
      size_t gb = (size_t)(ccb * 128 + row) * KB + koffB + q * 8;
      async16(Bhp + gb, Bb + lb);
      async16(Blp + gb, Bb + 8192 + lb);
    }
  }
}

template<int KTn>
__device__ __forceinline__ void read_frags_fn(
    const char* Ab, const char* Bb, int m, int quad, int mrow0, int nco0,
    short8 (&Ah)[4], short8 (&Al)[4], short8 (&RBh)[3], short8 (&RBl)[3]) {
  #pragma unroll
  for (int jj = 0; jj < 3; jj++) {
    const int jsel = (jj == 2) ? ((KTn < 10) ? 2 : 3) : jj;
    int br = nco0 + jsel * 16 + m;
    int bd = br * 64 + ((quad ^ ((br >> 1) & 3)) * 16);
    RBh[jj] = *(const short8*)(Bb + bd);
    RBl[jj] = *(const short8*)(Bb + 8192 + bd);
  }
  #pragma unroll
  for (int mt = 0; mt < 4; mt++) {
    int r = mrow0 + mt * 16 + m;
    int ad = r * 64 + ((quad ^ ((r >> 1) & 3)) * 16);
    Ah[mt] = *(const short8*)(Ab + ad);
    Al[mt] = *(const short8*)(Ab + 8192 + ad);
  }
}

template<int KT>
__device__ __forceinline__ void mfma_fn(
    const short8 (&Ah)[4], const short8 (&Al)[4],
    const short8 (&MBh)[3], const short8 (&MBl)[3], float4v (&acc)[4][4]) {
  #pragma unroll
  for (int mt = 0; mt < 4; mt++) {
    #pragma unroll
    for (int jj = 0; jj < 3; jj++) {
      const int J = (KT < 10) ? jj : ((jj == 2) ? 3 : jj);
      acc[mt][J] = __builtin_amdgcn_mfma_f32_16x16x32_bf16(Ah[mt], MBh[jj], acc[mt][J], 0, 0, 0);
      acc[mt][J] = __builtin_amdgcn_mfma_f32_16x16x32_bf16(Ah[mt], MBl[jj], acc[mt][J], 0, 0, 0);
      acc[mt][J] = __builtin_amdgcn_mfma_f32_16x16x32_bf16(Al[mt], MBh[jj], acc[mt][J], 0, 0, 0);
    }
  }
}

template<int KT>
__device__ __forceinline__ void gemm_step(
    const u16* __restrict__ Shp, const u16* __restrict__ Slp,
    const u16* __restrict__ nhc, const u16* __restrict__ nlc,
    const u16* __restrict__ Bhp, const u16* __restrict__ Blp,
    char (&Abuf)[16384], char (&Bbuf)[16384],
    int tid, int w, int m, int quad, int mrow0, int nco0, int r0, int ccb,
    float4v (&acc)[4][4]) {
  short8 Ah[4], Al[4], FBh[3], FBl[3];
  // 1. read frags(KT) from the single buffer
  read_frags_fn<KT>(Abuf, Bbuf, m, quad, mrow0, nco0, Ah, Al, FBh, FBl);
  asm volatile("s_waitcnt lgkmcnt(0)" ::: "memory");
  __builtin_amdgcn_sched_barrier(0);
  __builtin_amdgcn_s_barrier();                 // all waves done reading buffer
  // 2. stage(KT+1) into the same buffer (issue early, latency hidden by MFMA)
  if constexpr (KT + 1 <= 14)
    stage_fn<KT + 1>(Shp, Slp, nhc, nlc, Bhp, Blp, Abuf, Bbuf, tid, w, r0, ccb);
  __builtin_amdgcn_sched_barrier(0);
  // 3. MFMA(KT) from regs (matrix pipe runs while stage loads are in flight)
  __builtin_amdgcn_s_setprio(1);
  mfma_fn<KT>(Ah, Al, FBh, FBl, acc);
  __builtin_amdgcn_s_setprio(0);
  __builtin_amdgcn_sched_barrier(0);
  // 4. stage(KT+1) complete before next step's reads
  if constexpr (KT + 1 <= 14) {
    asm volatile("s_waitcnt vmcnt(0)" ::: "memory");
    __builtin_amdgcn_sched_barrier(0);
    __builtin_amdgcn_s_barrier();
  }
}

__global__ __launch_bounds__(256, 4) void gru_gemm_kernel(
    const u16* __restrict__ Shp, const u16* __restrict__ Slp,
    const u16* __restrict__ nhc, const u16* __restrict__ nlc,
    const u16* __restrict__ Bhp, const u16* __restrict__ Blp,
    const float* __restrict__ coefs, const int* __restrict__ rowptr,
    u16* __restrict__ nhn, u16* __restrict__ nln) {
  __shared__ char Abuf[16384];  // [0,8K)=hi plane, [8K,16K)=lo plane; 128 rows x 64B
  __shared__ char Bbuf[16384];  // [0,8K)=hi, [8K,16K)=lo
  const int bid = blockIdx.x;
  const int xcd = bid & 7;
  const int rest = bid >> 3;
  const int ccb = rest % 5;
  const int r0b = (rest / 5) * 8 + xcd;
  if (r0b >= NRB) return;
  const int r0 = r0b * 128;
  const int tid = threadIdx.x;
  const int w = tid >> 6, l = tid & 63;
  const int m = l & 15, quad = l >> 4;
  const int mrow0 = (w & 1) * 64;
  const int nco0 = (w >> 1) * 64;

  float4v acc[4][4];
  #pragma unroll
  for (int mt = 0; mt < 4; mt++)
    #pragma unroll
    for (int j = 0; j < 4; j++) acc[mt][j] = (float4v){0.f, 0.f, 0.f, 0.f};

  // ---- prologue: stage kt=0, drain, barrier ----
  stage_fn<0>(Shp, Slp, nhc, nlc, Bhp, Blp, Abuf, Bbuf, tid, w, r0, ccb);
  asm volatile("s_waitcnt vmcnt(0)" ::: "memory");
  __builtin_amdgcn_sched_barrier(0);
  __builtin_amdgcn_s_barrier();

  // ---- 15 fully-unrolled K-steps, 2 barriers each ----
  #define STEP(K) gemm_step<K>(Shp, Slp, nhc, nlc, Bhp, Blp, Abuf, Bbuf, tid, w, \
                               m, quad, mrow0, nco0, r0, ccb, acc)
  STEP(0);  STEP(1);  STEP(2);  STEP(3);  STEP(4);
  STEP(5);  STEP(6);  STEP(7);  STEP(8);  STEP(9);
  STEP(10); STEP(11); STEP(12); STEP(13); STEP(14);
  #undef STEP

  // ---- epilogue: wave handles c-chunk cc = ccb*2 + (w>>1); tile j = gate ----
  int c = (ccb * 2 + (w >> 1)) * 16 + m;
  if (c >= H) return;
  float u0r = coefs[c],            u0z = coefs[160 + c],
        u0n = coefs[320 + c];
  float u1r = coefs[VC + c],       u1z = coefs[VC + 160 + c],
        u1n = coefs[VC + 320 + c];
  float bsr = coefs[2 * VC + c],   bsz = coefs[2 * VC + 160 + c],
        bsn = coefs[2 * VC + 320 + c], bsh = coefs[2 * VC + 480 + c];
  #pragma unroll
  for (int mt = 0; mt < 4; mt++) {
    #pragma unroll
    for (int i = 0; i < 4; i++) {
      int row = r0 + mrow0 + mt * 16 + quad * 4 + i;
      if (row >= NN) continue;
      float d0 = (float)(rowptr[2 * row + 1] - rowptr[2 * row]);
      float d1 = (float)(rowptr[2 * row + 2] - rowptr[2 * row + 1]);
      float pr = acc[mt][0][i] + d0 * u0r + d1 * u1r + bsr;
      float pz = acc[mt][1][i] + d0 * u0z + d1 * u1z + bsz;
      float pn = acc[mt][2][i] + d0 * u0n + d1 * u1n + bsn;
      float ph = acc[mt][3][i] + bsh;
      float r_g = 1.f / (1.f + __expf(-pr));
      float z_g = 1.f / (1.f + __expf(-pz));
      float narg = pn + r_g * ph;
      float e2 = __expf(2.f * narg);
      float n_g = 1.f - 2.f / (e2 + 1.f);       // tanh, inf-safe
      size_t off = (size_t)row * 160 + c;
      float h = bf2f(nhc[off]) + bf2f(nlc[off]);
      u32 pw = packf((1.f - z_g) * n_g + z_g * h);
      nhn[off] = (u16)pw;
      nln[off] = (u16)(pw >> 16);
    }
  }
}

// ---------------- readout ----------------
__global__ __launch_bounds__(192) void segsum_kernel(const u16* __restrict__ nh,
                                                     const u16* __restrict__ nl,
                                                     const int* __restrict__ gstart,
                                                     float* __restrict__ gsum) {
  int g = blockIdx.x, chunk = blockIdx.y;
  int c = threadIdx.x;
  if (c >= H) return;
  int s = gstart[g], e = gstart[g + 1];
  int len = e - s;
  if (len <= 0) return;
  int per = (len + 3) / 4;
  int rs = s + chunk * per;
  int re = min(e, rs + per);
  if (rs >= re) return;
  float acc = 0.f;
  for (int r = rs; r < re; r++) {
    size_t off = (size_t)r * 160 + c;
    acc += bf2f(nh[off]) + bf2f(nl[off]);
  }
  atomicAdd(&gsum[g * H + c], acc);
}

// one block per graph row; 192 thr. LDS: x[151], x1[80], x2[80].
__global__ __launch_bounds__(192) void head_kernel(
    const float* __restrict__ gsum, const float* __restrict__ pt,
    const float* __restrict__ fc1_w, const float* __restrict__ fc1_b,
    const float* __restrict__ fc2_w, const float* __restrict__ fc2_b,
    const float* __restrict__ fcL_w, const float* __restrict__ fcL_b,
    float* __restrict__ out) {
  __shared__ float x[151];
  __shared__ float x1[80];
  __shared__ float x2[80];
  int row = blockIdx.x;
  int t = threadIdx.x;
  if (t < 151) {
    float v;
    if (t < H) { float g = gsum[row * H + t]; v = (g > 1.f) ? logf(g) : 0.f; }
    else v = pt[row];
    x[t] = v;
  }
  __syncthreads();
  if (t < 80) {
    float acc = fc1_b[t];
    const float* wrow = fc1_w + t * 151;
    #pragma unroll 4
    for (int k = 0; k < 151; k++) acc += x[k] * wrow[k];
    x1[t] = (acc > 0.f) ? acc : 0.01f * acc;
  }
  __syncthreads();
  if (t < 80) {
    float acc = fc2_b[t];
    const float* wrow = fc2_w + t * 80;
    #pragma unroll 4
    for (int k = 0; k < 80; k++) acc += x1[k] * wrow[k];
    x2[t] = (acc > 0.f) ? acc : 0.01f * acc;
  }
  __syncthreads();
  if (t < 10) {
    float acc = fcL_b[t];
    const float* wrow = fcL_w + t * 80;
    #pragma unroll 4
    for (int k = 0; k < 80; k++) acc += x2[k] * wrow[k];
    out[row * 10 + t] = acc;
  }
}

extern "C" void kernel_launch(void* const* d_in, const int* in_sizes, int n_in,
                              void* d_out, int out_size, void* d_ws, size_t ws_size,
                              hipStream_t stream) {
  const float* nodes_in = (const float*)d_in[0];
  const float* problem_type = (const float*)d_in[1];
  const float* edge_W = (const float*)d_in[2];
  const float* edge_b = (const float*)d_in[3];
  const float* w_ih = (const float*)d_in[4];
  const float* w_hh = (const float*)d_in[5];
  const float* b_ih = (const float*)d_in[6];
  const float* b_hh = (const float*)d_in[7];
  const float* fc1_w = (const float*)d_in[8];
  const float* fc1_b = (const float*)d_in[9];
  const float* fc2_w = (const float*)d_in[10];
  const float* fc2_b = (const float*)d_in[11];
  const float* fcL_w = (const float*)d_in[12];
  const float* fcL_b = (const float*)d_in[13];
  const int* edges = (const int*)d_in[14];
  const int* graph_ids = (const int*)d_in[15];

  char* ws = (char*)d_ws;
  size_t off = 0;
  auto alloc = [&](size_t bytes) -> void* {
    void* p = ws + off;
    off = (off + bytes + 255) & ~(size_t)255;
    return p;
  };
  u16* nhA      = (u16*)alloc((size_t)NN * 160 * 2);           // 16 MB
  u16* nlA      = (u16*)alloc((size_t)NN * 160 * 2);           // 16 MB
  u16* nhB      = (u16*)alloc((size_t)NN * 160 * 2);           // 16 MB
  u16* nlB      = (u16*)alloc((size_t)NN * 160 * 2);           // 16 MB
  u16* Sh       = (u16*)alloc((size_t)NN * 320 * 2);           // 32 MB
  u16* Sl       = (u16*)alloc((size_t)NN * 320 * 2);           // 32 MB
  u16* Bh       = (u16*)alloc((size_t)VC * KB * 2);            // 0.61 MB
  u16* Bl       = (u16*)alloc((size_t)VC * KB * 2);            // 0.61 MB
  float* coefs  = (float*)alloc(3 * VC * 4);
  int* rowptr   = (int*)alloc((2 * NN + 1) * 4);
  int* cursor   = (int*)alloc(2 * NN * 4);
  u16* colbuf   = (u16*)alloc(2ull * NE * 2);                  // 1.6 MB
  int* bsum     = (int*)alloc(128 * 4);
  int* boff     = (int*)alloc(128 * 4);
  int* gstart   = (int*)alloc((NG + 1) * 4);
  float* gsum   = (float*)alloc((size_t)NG * H * 4);

  const int n2 = 2 * NN;                 // 100000 counters
  const int nb = (n2 + 1023) / 1024;     // 98 scan blocks

  // ---- one-time setup ----
  hipMemsetAsync(cursor, 0, n2 * 4, stream);
  hist_kernel<<<(2 * NE + 255) / 256, 256, 0, stream>>>(edges, cursor);
  scan1_kernel<<<nb, 1024, 0, stream>>>(cursor, rowptr, bsum, n2);
  scan2_kernel<<<1, 128, 0, stream>>>(bsum, boff, nb);
  scan3_kernel<<<(n2 + 255) / 256, 256, 0, stream>>>(rowptr, boff, n2);
  total_kernel<<<1, 64, 0, stream>>>(rowptr, boff, n2, nb);
  copy_int_kernel<<<(n2 + 255) / 256, 256, 0, stream>>>(rowptr, cursor, n2);
  fill_kernel<<<(2 * NE + 255) / 256, 256, 0, stream>>>(edges, cursor, colbuf);
  bounds_kernel<<<1, 128, 0, stream>>>(graph_ids, gstart);
  build_B_kernel<<<(VC * KB + 255) / 256, 256, 0, stream>>>(w_ih, w_hh, edge_W, Bh, Bl);
  build_coef_kernel<<<(VC + 255) / 256, 256, 0, stream>>>(w_ih, edge_b, b_ih, b_hh, coefs);
  init_nodes_kernel<<<(NN * 160 + 255) / 256, 256, 0, stream>>>(nodes_in, nhA, nlA, nhB, nlB);
  pad_S_kernel<<<(NN * 20 + 255) / 256, 256, 0, stream>>>(Sh, Sl);

  // ---- 5 message-passing iterations (split-plane nodes ping-pong) ----
  const int ngrp = (NRB + 7) / 8;        // 49 groups of 8 row-blocks
  u16* nhb[2] = {nhA, nhB};
  u16* nlb[2] = {nlA, nlB};
  for (int pass = 0; pass < NPASS; pass++) {
    u16* nhc = nhb[pass & 1];
    u16* nlc = nlb[pass & 1];
    u16* nhn = nhb[1 - (pass & 1)];
    u16* nln = nlb[1 - (pass & 1)];
    gather_kernel<<<(2 * NN * 64 + 255) / 256, 256, 0, stream>>>(
        nhc, nlc, rowptr, colbuf, Sh, Sl);
    gru_gemm_kernel<<<ngrp * 5 * 8, 256, 0, stream>>>(
        Sh, Sl, nhc, nlc, Bh, Bl, coefs, rowptr, nhn, nln);
  }
  u16* finh = nhb[NPASS & 1];
  u16* finl = nlb[NPASS & 1];

  // ---- readout ----
  hipMemsetAsync(gsum, 0, (size_t)NG * H * 4, stream);
  segsum_kernel<<<dim3(NG, 4), 192, 0, stream>>>(finh, finl, gstart, gsum);
  head_kernel<<<NG, 192, 0, stream>>>(gsum, problem_type, fc1_w, fc1_b, fc2_w, fc2_b,
                                      fcL_w, fcL_b, (float*)d_out);
}

// Round 8
// 1128.434 us; speedup vs baseline: 1.1109x; 1.1109x over previous
//
#include <hip/hip_runtime.h>
#include <stdint.h>

#define NN 50000
#define H 150
#define NE 400000
#define NG 64
#define NPASS 5
#define KB 480          // GRU GEMM K: [S0(160) | S1(160) | nodes(160)]
#define VC 640          // 40 col-tiles: v = cc*64 + g*16 + cl, c = cc*16+cl
#define NRB 391         // row blocks of 128

typedef unsigned short u16;
typedef unsigned int u32;
typedef __attribute__((ext_vector_type(8))) short short8;
typedef __attribute__((ext_vector_type(4))) float float4v;
typedef __attribute__((ext_vector_type(4))) u32 uint4v;

// ---------------- helpers ----------------
__device__ __forceinline__ u16 f2bf_rn(float x) {
  union { float f; u32 u; } v; v.f = x;
  u32 r = v.u + 0x7fffu + ((v.u >> 16) & 1u);
  return (u16)(r >> 16);
}
__device__ __forceinline__ float bf2f(u16 h) {
  union { u32 u; float f; } v; v.u = ((u32)h) << 16;
  return v.f;
}
// packed word: low16 = hi bf16, high16 = lo bf16; value = hi + lo
__device__ __forceinline__ u32 packf(float v) {
  u16 hi = f2bf_rn(v);
  u16 lo = f2bf_rn(v - bf2f(hi));
  return (u32)hi | ((u32)lo << 16);
}
__device__ __forceinline__ float upk(u32 u) {
  union { u32 u; float f; } a, b;
  a.u = u << 16; b.u = u & 0xffff0000u;
  return a.f + b.f;
}
// async global->LDS, 16B per lane; lds dest must be wave-uniform base
__device__ __forceinline__ void async16(const void* g, void* l) {
  __builtin_amdgcn_global_load_lds(
      (const __attribute__((address_space(1))) unsigned int*)(uintptr_t)g,
      (__attribute__((address_space(3))) unsigned int*)(uint32_t)(uintptr_t)l,
      16, 0, 0);
}

// ---------------- CSR build (key = node*2 + set) ----------------
__global__ void hist_kernel(const int* __restrict__ edges, int* __restrict__ cnt) {
  int id = blockIdx.x * 256 + threadIdx.x;
  if (id >= 2 * NE) return;
  int dst = edges[id * 2];
  int set = id / NE;
  atomicAdd(&cnt[dst * 2 + set], 1);
}

__global__ __launch_bounds__(1024) void scan1_kernel(const int* __restrict__ cnt,
                                                     int* __restrict__ rowptr,
                                                     int* __restrict__ bsum, int n) {
  __shared__ int sd[1024];
  int t = threadIdx.x;
  int idx = blockIdx.x * 1024 + t;
  int v = (idx < n) ? cnt[idx] : 0;
  sd[t] = v;
  __syncthreads();
  for (int off = 1; off < 1024; off <<= 1) {
    int add = (t >= off) ? sd[t - off] : 0;
    __syncthreads();
    sd[t] += add;
    __syncthreads();
  }
  if (idx < n) rowptr[idx] = sd[t] - v;     // block-local exclusive
  if (t == 1023) bsum[blockIdx.x] = sd[1023];
}

__global__ __launch_bounds__(128) void scan2_kernel(const int* __restrict__ bsum,
                                                    int* __restrict__ boff, int nb) {
  __shared__ int sd[128];
  int t = threadIdx.x;
  int v = (t < nb) ? bsum[t] : 0;
  sd[t] = v;
  __syncthreads();
  for (int off = 1; off < 128; off <<= 1) {
    int add = (t >= off) ? sd[t - off] : 0;
    __syncthreads();
    sd[t] += add;
    __syncthreads();
  }
  boff[t] = sd[t] - v;                       // exclusive; boff[nb] = total
}

__global__ void scan3_kernel(int* __restrict__ rowptr, const int* __restrict__ boff, int n) {
  int idx = blockIdx.x * 256 + threadIdx.x;
  if (idx < n) rowptr[idx] += boff[idx >> 10];
}

__global__ void total_kernel(int* __restrict__ rowptr, const int* __restrict__ boff, int n, int nb) {
  if (threadIdx.x == 0 && blockIdx.x == 0) rowptr[n] = boff[nb];
}

__global__ void copy_int_kernel(const int* __restrict__ a, int* __restrict__ b, int n) {
  int id = blockIdx.x * 256 + threadIdx.x;
  if (id < n) b[id] = a[id];
}

__global__ void fill_kernel(const int* __restrict__ edges, int* __restrict__ cursor,
                            u16* __restrict__ colbuf) {
  int id = blockIdx.x * 256 + threadIdx.x;
  if (id >= 2 * NE) return;
  int dst = edges[id * 2];
  int src = edges[id * 2 + 1];
  int set = id / NE;
  int pos = atomicAdd(&cursor[dst * 2 + set], 1);
  colbuf[pos] = (u16)src;
}

__global__ void bounds_kernel(const int* __restrict__ gids, int* __restrict__ gstart) {
  int g = threadIdx.x;
  if (g > NG) return;
  int lo = 0, hi = NN;
  while (lo < hi) { int m = (lo + hi) >> 1; if (gids[m] < g) lo = m + 1; else hi = m; }
  gstart[g] = lo;
}

// ---------------- one-time weight prep ----------------
// B'[v][k], v in [0,640): g=(v>>4)&3, c=(v>>6)*16+(v&15)
// k<160: (W_ihg @ W0)[c][k]      (g<3; g3=0)
// 160<=k<320: (W_ihg @ W1)[c][k-160]
// 320<=k<480: g0: w_hh[c][kk], g1: w_hh[150+c][kk], g3: w_hh[300+c][kk], g2: 0
__global__ void build_B_kernel(const float* __restrict__ wih, const float* __restrict__ whh,
                               const float* __restrict__ eW,
                               u16* __restrict__ Bh, u16* __restrict__ Bl) {
  int id = blockIdx.x * 256 + threadIdx.x;
  if (id >= VC * KB) return;
  int v = id / KB, k = id % KB;
  int g = (v >> 4) & 3, c = (v >> 6) * 16 + (v & 15);
  int seg = k / 160, kk = k % 160;
  float val = 0.f;
  if (c < H && kk < H) {
    if (seg < 2) {
      if (g < 3) {
        const float* wr = wih + (size_t)(g * H + c) * H;
        const float* wc = eW + (size_t)seg * H * H + kk;
        float acc = 0.f;
        for (int t = 0; t < H; t++) acc += wr[t] * wc[(size_t)t * H];
        val = acc;
      }
    } else {
      if (g == 0) val = whh[(size_t)c * H + kk];
      else if (g == 1) val = whh[(size_t)(H + c) * H + kk];
      else if (g == 3) val = whh[(size_t)(2 * H + c) * H + kk];
    }
  }
  u16 h = f2bf_rn(val);
  Bh[id] = h;
  Bl[id] = f2bf_rn(val - bf2f(h));
}

// coefs[0][g*160+c] = W_ihg @ b0 (deg0 coef), coefs[1] = W_ihg @ b1, coefs[2] = gate bias
__global__ void build_coef_kernel(const float* __restrict__ wih,
                                  const float* __restrict__ eb,
                                  const float* __restrict__ bih, const float* __restrict__ bhh,
                                  float* __restrict__ coefs) {
  int id = threadIdx.x + blockIdx.x * 256;
  if (id >= VC) return;
  int g = id / 160, c = id % 160;
  float u0 = 0.f, u1 = 0.f, bs = 0.f;
  if (c < H) {
    if (g < 3) {
      const float* wr = wih + (size_t)(g * H + c) * H;
      for (int t = 0; t < H; t++) { u0 += wr[t] * eb[t]; u1 += wr[t] * eb[H + t]; }
    }
    if (g == 0) bs = bih[c] + bhh[c];
    else if (g == 1) bs = bih[H + c] + bhh[H + c];
    else if (g == 2) bs = bih[2 * H + c];
    else bs = bhh[2 * H + c];
  }
  coefs[id] = u0;
  coefs[VC + id] = u1;
  coefs[2 * VC + id] = bs;
}

// pack input nodes into npkA; zero pad cols of both buffers
__global__ void init_nodes_kernel(const float* __restrict__ nin,
                                  u32* __restrict__ npkA, u32* __restrict__ npkB) {
  int id = blockIdx.x * 256 + threadIdx.x;
  if (id >= NN * 160) return;
  int r = id / 160, c = id % 160;
  if (c < H) {
    npkA[id] = packf(nin[(size_t)r * H + c]);
  } else {
    npkA[id] = 0;
    npkB[id] = 0;
  }
}

// zero the pad columns of packed S (cols 150..159 per set); gather also writes
// them (sums of zero pad cols of npk) — same value, kept for first-pass safety
__global__ void pad_S_kernel(u32* __restrict__ Snp) {
  int id = blockIdx.x * 256 + threadIdx.x;
  if (id >= NN * 20) return;
  int r = id / 20, rem = id % 20;
  int set = rem / 10, t = rem % 10;
  Snp[(size_t)r * 320 + set * 160 + H + t] = 0;
}

// ---------------- gather: Snp[n][set*160+c] = packed sum of raw node rows ------
// R18: ONE VMEM instruction per edge. Lane l<40 loads the edge row's cols
// 4l..4l+3 as a single uint4 (40 lanes x 16B = the full 640B row); lanes 40-63
// exec-masked off. Requests/edge: 2.34 -> 1.0 (R17's accidental A/B showed the
// gather responds to request rate, not bytes). Adjacency list still loaded
// coalesced once per 64 edges + readlane broadcast; 4-edge unroll.
// Per-column accumulation order identical to R16 ((e0+e1) then (e2+e3), CSR
// sequence) -> bit-identical results.
__global__ __launch_bounds__(256) void gather_kernel(
    const u32* __restrict__ npk, const int* __restrict__ rowptr,
    const u16* __restrict__ colbuf, u32* __restrict__ Snp) {
  int gtid = blockIdx.x * 256 + threadIdx.x;
  int wid = gtid >> 6;
  if (wid >= 2 * NN) return;
  int node = wid >> 1, set = wid & 1;
  int lane = gtid & 63;
  int s = rowptr[2 * node + set], e = rowptr[2 * node + set + 1];
  int deg = e - s;
  int c4 = 4 * lane;
  bool ok = (lane < 40);               // cols 0..159 in 40 lanes
  float a0 = 0.f, a1 = 0.f, a2 = 0.f, a3 = 0.f;
  for (int base = 0; base < deg; base += 64) {
    int rem = min(64, deg - base);
    u32 srcv = 0;
    if (lane < rem) srcv = (u32)colbuf[s + base + lane];
    int i = 0;
    for (; i + 3 < rem; i += 4) {
      int r0 = __builtin_amdgcn_readlane((int)srcv, i);
      int r1 = __builtin_amdgcn_readlane((int)srcv, i + 1);
      int r2 = __builtin_amdgcn_readlane((int)srcv, i + 2);
      int r3 = __builtin_amdgcn_readlane((int)srcv, i + 3);
      uint4v v0 = {0, 0, 0, 0}, v1 = {0, 0, 0, 0};
      uint4v v2 = {0, 0, 0, 0}, v3 = {0, 0, 0, 0};
      if (ok) {
        v0 = *(const uint4v*)(npk + (size_t)(u32)r0 * 160 + c4);
        v1 = *(const uint4v*)(npk + (size_t)(u32)r1 * 160 + c4);
        v2 = *(const uint4v*)(npk + (size_t)(u32)r2 * 160 + c4);
        v3 = *(const uint4v*)(npk + (size_t)(u32)r3 * 160 + c4);
      }
      a0 += upk(v0.x) + upk(v1.x);
      a1 += upk(v0.y) + upk(v1.y);
      a2 += upk(v0.z) + upk(v1.z);
      a3 += upk(v0.w) + upk(v1.w);
      a0 += upk(v2.x) + upk(v3.x);
      a1 += upk(v2.y) + upk(v3.y);
      a2 += upk(v2.z) + upk(v3.z);
      a3 += upk(v2.w) + upk(v3.w);
    }
    for (; i + 1 < rem; i += 2) {
      int r0 = __builtin_amdgcn_readlane((int)srcv, i);
      int r1 = __builtin_amdgcn_readlane((int)srcv, i + 1);
      uint4v v0 = {0, 0, 0, 0}, v1 = {0, 0, 0, 0};
      if (ok) {
        v0 = *(const uint4v*)(npk + (size_t)(u32)r0 * 160 + c4);
        v1 = *(const uint4v*)(npk + (size_t)(u32)r1 * 160 + c4);
      }
      a0 += upk(v0.x) + upk(v1.x);
      a1 += upk(v0.y) + upk(v1.y);
      a2 += upk(v0.z) + upk(v1.z);
      a3 += upk(v0.w) + upk(v1.w);
    }
    if (i < rem) {
      int r0 = __builtin_amdgcn_readlane((int)srcv, i);
      uint4v v0 = {0, 0, 0, 0};
      if (ok) v0 = *(const uint4v*)(npk + (size_t)(u32)r0 * 160 + c4);
      a0 += upk(v0.x);
      a1 += upk(v0.y);
      a2 += upk(v0.z);
      a3 += upk(v0.w);
    }
  }
  if (ok) {
    uint4v pv;
    pv.x = packf(a0);
    pv.y = packf(a1);
    pv.z = packf(a2);
    pv.w = packf(a3);
    *(uint4v*)(Snp + (size_t)node * 320 + set * 160 + c4) = pv;
  }
}

// ---------------- fused GRU GEMM — R16 verbatim (best measured: 101.6 us) -----
// Single 32KB buffer set, 2-phase per kt, 4 blocks/CU budget. R17 proved the
// packed-format VALU unpack and the 3.75M bank conflicts are NOT the binder
// (removing both made it slower), so the packed version stays.

template<int KT>
__device__ __forceinline__ void stage_fn(
    const u32* __restrict__ Snp, const u32* __restrict__ npkc,
    const u16* __restrict__ Bhp, const u16* __restrict__ Blp,
    char* Ab, char* Bb, int tid, int w, int r0, int ccb) {
  // A tile: 128 rows x 32 k-cols packed u32 = 128B/row, XOR-swizzled chunks
  #pragma unroll
  for (int i = 0; i < 4; i++) {
    int cl = i * 256 + tid;                     // [0,1024)
    int row = cl >> 3;
    int q = (cl & 7) ^ (row & 7);
    int rg = min(r0 + row, NN - 1);
    if constexpr (KT < 10)
      async16(Snp + (size_t)rg * 320 + KT * 32 + q * 4, Ab + i * 4096 + w * 1024);
    else
      async16(npkc + (size_t)rg * 160 + (KT - 10) * 32 + q * 4, Ab + i * 4096 + w * 1024);
  }
  constexpr int koffB = (KT < 10) ? KT * 32 : 320 + (KT - 10) * 32;
  constexpr int skipg = (KT < 10) ? 3 : 2;      // zero-gate rows (exact skip)
  #pragma unroll
  for (int i = 0; i < 2; i++) {
    int cl = i * 256 + tid;                     // [0,512)
    int row = cl >> 2;
    int q = (cl & 3) ^ ((row >> 1) & 3);
    if (((row >> 4) & 3) != skipg) {            // wave-uniform predicate
      size_t gb = (size_t)(ccb * 128 + row) * KB + koffB + q * 8;
      int lb = i * 4096 + w * 1024;
      async16(Bhp + gb, Bb + lb);
      async16(Blp + gb, Bb + 8192 + lb);
    }
  }
}

template<int KTn>
__device__ __forceinline__ void read_frags_fn(
    const char* Ab, const char* Bb, int m, int quad, int mrow0, int nco0,
    uint4v (&A0)[4], uint4v (&A1)[4], short8 (&RBh)[3], short8 (&RBl)[3]) {
  #pragma unroll
  for (int jj = 0; jj < 3; jj++) {
    const int jsel = (jj == 2) ? ((KTn < 10) ? 2 : 3) : jj;
    int br = nco0 + jsel * 16 + m;
    int bd = br * 64 + ((quad ^ ((br >> 1) & 3)) * 16);
    RBh[jj] = *(const short8*)(Bb + bd);
    RBl[jj] = *(const short8*)(Bb + 8192 + bd);
  }
  #pragma unroll
  for (int mt = 0; mt < 4; mt++) {
    int r = mrow0 + mt * 16 + m;
    A0[mt] = *(const uint4v*)(Ab + r * 128 + (((2 * quad) ^ (r & 7)) * 16));
    A1[mt] = *(const uint4v*)(Ab + r * 128 + (((2 * quad + 1) ^ (r & 7)) * 16));
  }
}

template<int KT>
__device__ __forceinline__ void mfma_fn(
    const uint4v (&A0)[4], const uint4v (&A1)[4],
    const short8 (&MBh)[3], const short8 (&MBl)[3], float4v (&acc)[4][4]) {
  #pragma unroll
  for (int mt = 0; mt < 4; mt++) {
    u32 uu[8] = {A0[mt].x, A0[mt].y, A0[mt].z, A0[mt].w,
                 A1[mt].x, A1[mt].y, A1[mt].z, A1[mt].w};
    short8 ah, al;
    #pragma unroll
    for (int e2 = 0; e2 < 8; e2++) {
      ah[e2] = (short)(uu[e2] & 0xffffu);
      al[e2] = (short)(uu[e2] >> 16);
    }
    #pragma unroll
    for (int jj = 0; jj < 3; jj++) {
      const int J = (KT < 10) ? jj : ((jj == 2) ? 3 : jj);
      acc[mt][J] = __builtin_amdgcn_mfma_f32_16x16x32_bf16(ah, MBh[jj], acc[mt][J], 0, 0, 0);
      acc[mt][J] = __builtin_amdgcn_mfma_f32_16x16x32_bf16(ah, MBl[jj], acc[mt][J], 0, 0, 0);
      acc[mt][J] = __builtin_amdgcn_mfma_f32_16x16x32_bf16(al, MBh[jj], acc[mt][J], 0, 0, 0);
    }
  }
}

template<int KT>
__device__ __forceinline__ void gemm_step(
    const u32* __restrict__ Snp, const u32* __restrict__ npkc,
    const u16* __restrict__ Bhp, const u16* __restrict__ Blp,
    char (&Abuf)[16384], char (&Bbuf)[16384],
    int tid, int w, int m, int quad, int mrow0, int nco0, int r0, int ccb,
    float4v (&acc)[4][4]) {
  uint4v A0[4], A1[4];
  short8 FBh[3], FBl[3];
  // 1. read frags(KT) from the single buffer
  read_frags_fn<KT>(Abuf, Bbuf, m, quad, mrow0, nco0, A0, A1, FBh, FBl);
  asm volatile("s_waitcnt lgkmcnt(0)" ::: "memory");
  __builtin_amdgcn_sched_barrier(0);
  __builtin_amdgcn_s_barrier();                 // all waves done reading buffer
  // 2. stage(KT+1) into the same buffer (issue early, latency hidden by MFMA)
  if constexpr (KT + 1 <= 14)
    stage_fn<KT + 1>(Snp, npkc, Bhp, Blp, Abuf, Bbuf, tid, w, r0, ccb);
  __builtin_amdgcn_sched_barrier(0);
  // 3. MFMA(KT) from regs (matrix pipe runs while stage loads are in flight)
  __builtin_amdgcn_s_setprio(1);
  mfma_fn<KT>(A0, A1, FBh, FBl, acc);
  __builtin_amdgcn_s_setprio(0);
  __builtin_amdgcn_sched_barrier(0);
  // 4. stage(KT+1) complete before next step's reads
  if constexpr (KT + 1 <= 14) {
    asm volatile("s_waitcnt vmcnt(0)" ::: "memory");
    __builtin_amdgcn_sched_barrier(0);
    __builtin_amdgcn_s_barrier();
  }
}

__global__ __launch_bounds__(256, 4) void gru_gemm_kernel(
    const u32* __restrict__ Snp, const u32* __restrict__ npkc,
    const u16* __restrict__ Bhp, const u16* __restrict__ Blp,
    const float* __restrict__ coefs, const int* __restrict__ rowptr,
    u32* __restrict__ npkn) {
  __shared__ char Abuf[16384];  // packed u32 A tile: 128 rows x 128B, XOR swizzle
  __shared__ char Bbuf[16384];  // [0,8K)=hi, [8K,16K)=lo
  const int bid = blockIdx.x;
  const int xcd = bid & 7;
  const int rest = bid >> 3;
  const int ccb = rest % 5;
  const int r0b = (rest / 5) * 8 + xcd;
  if (r0b >= NRB) return;
  const int r0 = r0b * 128;
  const int tid = threadIdx.x;
  const int w = tid >> 6, l = tid & 63;
  const int m = l & 15, quad = l >> 4;
  const int mrow0 = (w & 1) * 64;
  const int nco0 = (w >> 1) * 64;

  float4v acc[4][4];
  #pragma unroll
  for (int mt = 0; mt < 4; mt++)
    #pragma unroll
    for (int j = 0; j < 4; j++) acc[mt][j] = (float4v){0.f, 0.f, 0.f, 0.f};

  // ---- prologue: stage kt=0, drain, barrier ----
  stage_fn<0>(Snp, npkc, Bhp, Blp, Abuf, Bbuf, tid, w, r0, ccb);
  asm volatile("s_waitcnt vmcnt(0)" ::: "memory");
  __builtin_amdgcn_sched_barrier(0);
  __builtin_amdgcn_s_barrier();

  // ---- 15 fully-unrolled K-steps, 2 barriers each ----
  #define STEP(K) gemm_step<K>(Snp, npkc, Bhp, Blp, Abuf, Bbuf, tid, w, m, quad, \
                               mrow0, nco0, r0, ccb, acc)
  STEP(0);  STEP(1);  STEP(2);  STEP(3);  STEP(4);
  STEP(5);  STEP(6);  STEP(7);  STEP(8);  STEP(9);
  STEP(10); STEP(11); STEP(12); STEP(13); STEP(14);
  #undef STEP

  // ---- epilogue: wave handles c-chunk cc = ccb*2 + (w>>1); tile j = gate ----
  int c = (ccb * 2 + (w >> 1)) * 16 + m;
  if (c >= H) return;
  float u0r = coefs[c],            u0z = coefs[160 + c],
        u0n = coefs[320 + c];
  float u1r = coefs[VC + c],       u1z = coefs[VC + 160 + c],
        u1n = coefs[VC + 320 + c];
  float bsr = coefs[2 * VC + c],   bsz = coefs[2 * VC + 160 + c],
        bsn = coefs[2 * VC + 320 + c], bsh = coefs[2 * VC + 480 + c];
  #pragma unroll
  for (int mt = 0; mt < 4; mt++) {
    #pragma unroll
    for (int i = 0; i < 4; i++) {
      int row = r0 + mrow0 + mt * 16 + quad * 4 + i;
      if (row >= NN) continue;
      float d0 = (float)(rowptr[2 * row + 1] - rowptr[2 * row]);
      float d1 = (float)(rowptr[2 * row + 2] - rowptr[2 * row + 1]);
      float pr = acc[mt][0][i] + d0 * u0r + d1 * u1r + bsr;
      float pz = acc[mt][1][i] + d0 * u0z + d1 * u1z + bsz;
      float pn = acc[mt][2][i] + d0 * u0n + d1 * u1n + bsn;
      float ph = acc[mt][3][i] + bsh;
      float r_g = 1.f / (1.f + __expf(-pr));
      float z_g = 1.f / (1.f + __expf(-pz));
      float narg = pn + r_g * ph;
      float e2 = __expf(2.f * narg);
      float n_g = 1.f - 2.f / (e2 + 1.f);       // tanh, inf-safe
      float h = upk(npkc[(size_t)row * 160 + c]);
      npkn[(size_t)row * 160 + c] = packf((1.f - z_g) * n_g + z_g * h);
    }
  }
}

// ---------------- readout ----------------
__global__ __launch_bounds__(192) void segsum_kernel(const u32* __restrict__ npk,
                                                     const int* __restrict__ gstart,
                                                     float* __restrict__ gsum) {
  int g = blockIdx.x, chunk = blockIdx.y;
  int c = threadIdx.x;
  if (c >= H) return;
  int s = gstart[g], e = gstart[g + 1];
  int len = e - s;
  if (len <= 0) return;
  int per = (len + 3) / 4;
  int rs = s + chunk * per;
  int re = min(e, rs + per);
  if (rs >= re) return;
  float acc = 0.f;
  for (int r = rs; r < re; r++) acc += upk(npk[(size_t)r * 160 + c]);
  atomicAdd(&gsum[g * H + c], acc);
}

// one block per graph row; 192 thr. LDS: x[151], x1[80], x2[80].
__global__ __launch_bounds__(192) void head_kernel(
    const float* __restrict__ gsum, const float* __restrict__ pt,
    const float* __restrict__ fc1_w, const float* __restrict__ fc1_b,
    const float* __restrict__ fc2_w, const float* __restrict__ fc2_b,
    const float* __restrict__ fcL_w, const float* __restrict__ fcL_b,
    float* __restrict__ out) {
  __shared__ float x[151];
  __shared__ float x1[80];
  __shared__ float x2[80];
  int row = blockIdx.x;
  int t = threadIdx.x;
  if (t < 151) {
    float v;
    if (t < H) { float g = gsum[row * H + t]; v = (g > 1.f) ? logf(g) : 0.f; }
    else v = pt[row];
    x[t] = v;
  }
  __syncthreads();
  if (t < 80) {
    float acc = fc1_b[t];
    const float* wrow = fc1_w + t * 151;
    #pragma unroll 4
    for (int k = 0; k < 151; k++) acc += x[k] * wrow[k];
    x1[t] = (acc > 0.f) ? acc : 0.01f * acc;
  }
  __syncthreads();
  if (t < 80) {
    float acc = fc2_b[t];
    const float* wrow = fc2_w + t * 80;
    #pragma unroll 4
    for (int k = 0; k < 80; k++) acc += x1[k] * wrow[k];
    x2[t] = (acc > 0.f) ? acc : 0.01f * acc;
  }
  __syncthreads();
  if (t < 10) {
    float acc = fcL_b[t];
    const float* wrow = fcL_w + t * 80;
    #pragma unroll 4
    for (int k = 0; k < 80; k++) acc += x2[k] * wrow[k];
    out[row * 10 + t] = acc;
  }
}

extern "C" void kernel_launch(void* const* d_in, const int* in_sizes, int n_in,
                              void* d_out, int out_size, void* d_ws, size_t ws_size,
                              hipStream_t stream) {
  const float* nodes_in = (const float*)d_in[0];
  const float* problem_type = (const float*)d_in[1];
  const float* edge_W = (const float*)d_in[2];
  const float* edge_b = (const float*)d_in[3];
  const float* w_ih = (const float*)d_in[4];
  const float* w_hh = (const float*)d_in[5];
  const float* b_ih = (const float*)d_in[6];
  const float* b_hh = (const float*)d_in[7];
  const float* fc1_w = (const float*)d_in[8];
  const float* fc1_b = (const float*)d_in[9];
  const float* fc2_w = (const float*)d_in[10];
  const float* fc2_b = (const float*)d_in[11];
  const float* fcL_w = (const float*)d_in[12];
  const float* fcL_b = (const float*)d_in[13];
  const int* edges = (const int*)d_in[14];
  const int* graph_ids = (const int*)d_in[15];

  char* ws = (char*)d_ws;
  size_t off = 0;
  auto alloc = [&](size_t bytes) -> void* {
    void* p = ws + off;
    off = (off + bytes + 255) & ~(size_t)255;
    return p;
  };
  u32* npkA     = (u32*)alloc((size_t)NN * 160 * 4);           // 32 MB
  u32* npkB     = (u32*)alloc((size_t)NN * 160 * 4);           // 32 MB
  u32* Snp      = (u32*)alloc((size_t)NN * 320 * 4);           // 64 MB packed S
  u16* Bh       = (u16*)alloc((size_t)VC * KB * 2);            // 0.61 MB
  u16* Bl       = (u16*)alloc((size_t)VC * KB * 2);            // 0.61 MB
  float* coefs  = (float*)alloc(3 * VC * 4);
  int* rowptr   = (int*)alloc((2 * NN + 1) * 4);
  int* cursor   = (int*)alloc(2 * NN * 4);
  u16* colbuf   = (u16*)alloc(2ull * NE * 2);                  // 1.6 MB
  int* bsum     = (int*)alloc(128 * 4);
  int* boff     = (int*)alloc(128 * 4);
  int* gstart   = (int*)alloc((NG + 1) * 4);
  float* gsum   = (float*)alloc((size_t)NG * H * 4);

  const int n2 = 2 * NN;                 // 100000 counters
  const int nb = (n2 + 1023) / 1024;     // 98 scan blocks

  // ---- one-time setup ----
  hipMemsetAsync(cursor, 0, n2 * 4, stream);
  hist_kernel<<<(2 * NE + 255) / 256, 256, 0, stream>>>(edges, cursor);
  scan1_kernel<<<nb, 1024, 0, stream>>>(cursor, rowptr, bsum, n2);
  scan2_kernel<<<1, 128, 0, stream>>>(bsum, boff, nb);
  scan3_kernel<<<(n2 + 255) / 256, 256, 0, stream>>>(rowptr, boff, n2);
  total_kernel<<<1, 64, 0, stream>>>(rowptr, boff, n2, nb);
  copy_int_kernel<<<(n2 + 255) / 256, 256, 0, stream>>>(rowptr, cursor, n2);
  fill_kernel<<<(2 * NE + 255) / 256, 256, 0, stream>>>(edges, cursor, colbuf);
  bounds_kernel<<<1, 128, 0, stream>>>(graph_ids, gstart);
  build_B_kernel<<<(VC * KB + 255) / 256, 256, 0, stream>>>(w_ih, w_hh, edge_W, Bh, Bl);
  build_coef_kernel<<<(VC + 255) / 256, 256, 0, stream>>>(w_ih, edge_b, b_ih, b_hh, coefs);
  init_nodes_kernel<<<(NN * 160 + 255) / 256, 256, 0, stream>>>(nodes_in, npkA, npkB);
  pad_S_kernel<<<(NN * 20 + 255) / 256, 256, 0, stream>>>(Snp);

  // ---- 5 message-passing iterations (packed nodes ping-pong) ----
  const int ngrp = (NRB + 7) / 8;        // 49 groups of 8 row-blocks
  u32* nbuf[2] = {npkA, npkB};
  for (int pass = 0; pass < NPASS; pass++) {
    u32* cur = nbuf[pass & 1];
    u32* nxt = nbuf[1 - (pass & 1)];
    gather_kernel<<<(2 * NN * 64 + 255) / 256, 256, 0, stream>>>(cur, rowptr, colbuf, Snp);
    gru_gemm_kernel<<<ngrp * 5 * 8, 256, 0, stream>>>(
        Snp, cur, Bh, Bl, coefs, rowptr, nxt);
  }
  u32* fin = nbuf[NPASS & 1];

  // ---- readout ----
  hipMemsetAsync(gsum, 0, (size_t)NG * H * 4, stream);
  segsum_kernel<<<dim3(NG, 4), 192, 0, stream>>>(fin, gstart, gsum);
  head_kernel<<<NG, 192, 0, stream>>>(gsum, problem_type, fc1_w, fc1_b, fc2_w, fc2_b,
                                      fcL_w, fcL_b, (float*)d_out);
}

// Round 9
// 1110.151 us; speedup vs baseline: 1.1292x; 1.0165x over previous
//
#include <hip/hip_runtime.h>
#include <stdint.h>

#define NN 50000
#define H 150
#define NE 400000
#define NG 64
#define NPASS 5
#define KB 480          // GRU GEMM K: [S0(160) | S1(160) | nodes(160)]
#define VC 640          // 40 col-tiles: v = cc*64 + g*16 + cl, c = cc*16+cl
#define NRB 391         // row blocks of 128

typedef unsigned short u16;
typedef unsigned int u32;
typedef __attribute__((ext_vector_type(8))) short short8;
typedef __attribute__((ext_vector_type(4))) float float4v;
typedef __attribute__((ext_vector_type(4))) u32 uint4v;

// ---------------- helpers ----------------
__device__ __forceinline__ u16 f2bf_rn(float x) {
  union { float f; u32 u; } v; v.f = x;
  u32 r = v.u + 0x7fffu + ((v.u >> 16) & 1u);
  return (u16)(r >> 16);
}
__device__ __forceinline__ float bf2f(u16 h) {
  union { u32 u; float f; } v; v.u = ((u32)h) << 16;
  return v.f;
}
// packed word: low16 = hi bf16, high16 = lo bf16; value = hi + lo
__device__ __forceinline__ u32 packf(float v) {
  u16 hi = f2bf_rn(v);
  u16 lo = f2bf_rn(v - bf2f(hi));
  return (u32)hi | ((u32)lo << 16);
}
__device__ __forceinline__ float upk(u32 u) {
  union { u32 u; float f; } a, b;
  a.u = u << 16; b.u = u & 0xffff0000u;
  return a.f + b.f;
}
// async global->LDS, 16B per lane; lds dest must be wave-uniform base
__device__ __forceinline__ void async16(const void* g, void* l) {
  __builtin_amdgcn_global_load_lds(
      (const __attribute__((address_space(1))) unsigned int*)(uintptr_t)g,
      (__attribute__((address_space(3))) unsigned int*)(uint32_t)(uintptr_t)l,
      16, 0, 0);
}

// ---------------- CSR build (key = node*2 + set) ----------------
__global__ void hist_kernel(const int* __restrict__ edges, int* __restrict__ cnt) {
  int id = blockIdx.x * 256 + threadIdx.x;
  if (id >= 2 * NE) return;
  int dst = edges[id * 2];
  int set = id / NE;
  atomicAdd(&cnt[dst * 2 + set], 1);
}

__global__ __launch_bounds__(1024) void scan1_kernel(const int* __restrict__ cnt,
                                                     int* __restrict__ rowptr,
                                                     int* __restrict__ bsum, int n) {
  __shared__ int sd[1024];
  int t = threadIdx.x;
  int idx = blockIdx.x * 1024 + t;
  int v = (idx < n) ? cnt[idx] : 0;
  sd[t] = v;
  __syncthreads();
  for (int off = 1; off < 1024; off <<= 1) {
    int add = (t >= off) ? sd[t - off] : 0;
    __syncthreads();
    sd[t] += add;
    __syncthreads();
  }
  if (idx < n) rowptr[idx] = sd[t] - v;     // block-local exclusive
  if (t == 1023) bsum[blockIdx.x] = sd[1023];
}

__global__ __launch_bounds__(128) void scan2_kernel(const int* __restrict__ bsum,
                                                    int* __restrict__ boff, int nb) {
  __shared__ int sd[128];
  int t = threadIdx.x;
  int v = (t < nb) ? bsum[t] : 0;
  sd[t] = v;
  __syncthreads();
  for (int off = 1; off < 128; off <<= 1) {
    int add = (t >= off) ? sd[t - off] : 0;
    __syncthreads();
    sd[t] += add;
    __syncthreads();
  }
  boff[t] = sd[t] - v;                       // exclusive; boff[nb] = total
}

__global__ void scan3_kernel(int* __restrict__ rowptr, const int* __restrict__ boff, int n) {
  int idx = blockIdx.x * 256 + threadIdx.x;
  if (idx < n) rowptr[idx] += boff[idx >> 10];
}

__global__ void total_kernel(int* __restrict__ rowptr, const int* __restrict__ boff, int n, int nb) {
  if (threadIdx.x == 0 && blockIdx.x == 0) rowptr[n] = boff[nb];
}

__global__ void copy_int_kernel(const int* __restrict__ a, int* __restrict__ b, int n) {
  int id = blockIdx.x * 256 + threadIdx.x;
  if (id < n) b[id] = a[id];
}

__global__ void fill_kernel(const int* __restrict__ edges, int* __restrict__ cursor,
                            u16* __restrict__ colbuf) {
  int id = blockIdx.x * 256 + threadIdx.x;
  if (id >= 2 * NE) return;
  int dst = edges[id * 2];
  int src = edges[id * 2 + 1];
  int set = id / NE;
  int pos = atomicAdd(&cursor[dst * 2 + set], 1);
  colbuf[pos] = (u16)src;
}

__global__ void bounds_kernel(const int* __restrict__ gids, int* __restrict__ gstart) {
  int g = threadIdx.x;
  if (g > NG) return;
  int lo = 0, hi = NN;
  while (lo < hi) { int m = (lo + hi) >> 1; if (gids[m] < g) lo = m + 1; else hi = m; }
  gstart[g] = lo;
}

// ---------------- one-time weight prep ----------------
// B'[v][k], v in [0,640): g=(v>>4)&3, c=(v>>6)*16+(v&15)
// k<160: (W_ihg @ W0)[c][k]      (g<3; g3=0)
// 160<=k<320: (W_ihg @ W1)[c][k-160]
// 320<=k<480: g0: w_hh[c][kk], g1: w_hh[150+c][kk], g3: w_hh[300+c][kk], g2: 0
__global__ void build_B_kernel(const float* __restrict__ wih, const float* __restrict__ whh,
                               const float* __restrict__ eW,
                               u16* __restrict__ Bh, u16* __restrict__ Bl) {
  int id = blockIdx.x * 256 + threadIdx.x;
  if (id >= VC * KB) return;
  int v = id / KB, k = id % KB;
  int g = (v >> 4) & 3, c = (v >> 6) * 16 + (v & 15);
  int seg = k / 160, kk = k % 160;
  float val = 0.f;
  if (c < H && kk < H) {
    if (seg < 2) {
      if (g < 3) {
        const float* wr = wih + (size_t)(g * H + c) * H;
        const float* wc = eW + (size_t)seg * H * H + kk;
        float acc = 0.f;
        for (int t = 0; t < H; t++) acc += wr[t] * wc[(size_t)t * H];
        val = acc;
      }
    } else {
      if (g == 0) val = whh[(size_t)c * H + kk];
      else if (g == 1) val = whh[(size_t)(H + c) * H + kk];
      else if (g == 3) val = whh[(size_t)(2 * H + c) * H + kk];
    }
  }
  u16 h = f2bf_rn(val);
  Bh[id] = h;
  Bl[id] = f2bf_rn(val - bf2f(h));
}

// coefs[0][g*160+c] = W_ihg @ b0 (deg0 coef), coefs[1] = W_ihg @ b1, coefs[2] = gate bias
__global__ void build_coef_kernel(const float* __restrict__ wih,
                                  const float* __restrict__ eb,
                                  const float* __restrict__ bih, const float* __restrict__ bhh,
                                  float* __restrict__ coefs) {
  int id = threadIdx.x + blockIdx.x * 256;
  if (id >= VC) return;
  int g = id / 160, c = id % 160;
  float u0 = 0.f, u1 = 0.f, bs = 0.f;
  if (c < H) {
    if (g < 3) {
      const float* wr = wih + (size_t)(g * H + c) * H;
      for (int t = 0; t < H; t++) { u0 += wr[t] * eb[t]; u1 += wr[t] * eb[H + t]; }
    }
    if (g == 0) bs = bih[c] + bhh[c];
    else if (g == 1) bs = bih[H + c] + bhh[H + c];
    else if (g == 2) bs = bih[2 * H + c];
    else bs = bhh[2 * H + c];
  }
  coefs[id] = u0;
  coefs[VC + id] = u1;
  coefs[2 * VC + id] = bs;
}

// pack input nodes into npkA; zero pad cols of both buffers
__global__ void init_nodes_kernel(const float* __restrict__ nin,
                                  u32* __restrict__ npkA, u32* __restrict__ npkB) {
  int id = blockIdx.x * 256 + threadIdx.x;
  if (id >= NN * 160) return;
  int r = id / 160, c = id % 160;
  if (c < H) {
    npkA[id] = packf(nin[(size_t)r * H + c]);
  } else {
    npkA[id] = 0;
    npkB[id] = 0;
  }
}

// zero the pad columns of packed S (cols 150..159 per set); gather also writes
// them (sums of zero pad cols of npk) — same value, kept for first-pass safety
__global__ void pad_S_kernel(u32* __restrict__ Snp) {
  int id = blockIdx.x * 256 + threadIdx.x;
  if (id >= NN * 20) return;
  int r = id / 20, rem = id % 20;
  int set = rem / 10, t = rem % 10;
  Snp[(size_t)r * 320 + set * 160 + H + t] = 0;
}

// ---------------- gather: Snp[n][set*160+c] = packed sum of raw node rows ------
// R18 form (1 VMEM/edge): lane l<40 loads cols 4l..4l+3 as one uint4; lanes
// 40-63 masked. Adjacency list loaded coalesced + readlane broadcast; 4-edge
// unroll. Gather is at its cache-line traffic floor (R17/R18 A/B established
// lines, not instructions or bytes, set its rate). Bit-identical accumulation.
__global__ __launch_bounds__(256) void gather_kernel(
    const u32* __restrict__ npk, const int* __restrict__ rowptr,
    const u16* __restrict__ colbuf, u32* __restrict__ Snp) {
  int gtid = blockIdx.x * 256 + threadIdx.x;
  int wid = gtid >> 6;
  if (wid >= 2 * NN) return;
  int node = wid >> 1, set = wid & 1;
  int lane = gtid & 63;
  int s = rowptr[2 * node + set], e = rowptr[2 * node + set + 1];
  int deg = e - s;
  int c4 = 4 * lane;
  bool ok = (lane < 40);               // cols 0..159 in 40 lanes
  float a0 = 0.f, a1 = 0.f, a2 = 0.f, a3 = 0.f;
  for (int base = 0; base < deg; base += 64) {
    int rem = min(64, deg - base);
    u32 srcv = 0;
    if (lane < rem) srcv = (u32)colbuf[s + base + lane];
    int i = 0;
    for (; i + 3 < rem; i += 4) {
      int r0 = __builtin_amdgcn_readlane((int)srcv, i);
      int r1 = __builtin_amdgcn_readlane((int)srcv, i + 1);
      int r2 = __builtin_amdgcn_readlane((int)srcv, i + 2);
      int r3 = __builtin_amdgcn_readlane((int)srcv, i + 3);
      uint4v v0 = {0, 0, 0, 0}, v1 = {0, 0, 0, 0};
      uint4v v2 = {0, 0, 0, 0}, v3 = {0, 0, 0, 0};
      if (ok) {
        v0 = *(const uint4v*)(npk + (size_t)(u32)r0 * 160 + c4);
        v1 = *(const uint4v*)(npk + (size_t)(u32)r1 * 160 + c4);
        v2 = *(const uint4v*)(npk + (size_t)(u32)r2 * 160 + c4);
        v3 = *(const uint4v*)(npk + (size_t)(u32)r3 * 160 + c4);
      }
      a0 += upk(v0.x) + upk(v1.x);
      a1 += upk(v0.y) + upk(v1.y);
      a2 += upk(v0.z) + upk(v1.z);
      a3 += upk(v0.w) + upk(v1.w);
      a0 += upk(v2.x) + upk(v3.x);
      a1 += upk(v2.y) + upk(v3.y);
      a2 += upk(v2.z) + upk(v3.z);
      a3 += upk(v2.w) + upk(v3.w);
    }
    for (; i + 1 < rem; i += 2) {
      int r0 = __builtin_amdgcn_readlane((int)srcv, i);
      int r1 = __builtin_amdgcn_readlane((int)srcv, i + 1);
      uint4v v0 = {0, 0, 0, 0}, v1 = {0, 0, 0, 0};
      if (ok) {
        v0 = *(const uint4v*)(npk + (size_t)(u32)r0 * 160 + c4);
        v1 = *(const uint4v*)(npk + (size_t)(u32)r1 * 160 + c4);
      }
      a0 += upk(v0.x) + upk(v1.x);
      a1 += upk(v0.y) + upk(v1.y);
      a2 += upk(v0.z) + upk(v1.z);
      a3 += upk(v0.w) + upk(v1.w);
    }
    if (i < rem) {
      int r0 = __builtin_amdgcn_readlane((int)srcv, i);
      uint4v v0 = {0, 0, 0, 0};
      if (ok) v0 = *(const uint4v*)(npk + (size_t)(u32)r0 * 160 + c4);
      a0 += upk(v0.x);
      a1 += upk(v0.y);
      a2 += upk(v0.z);
      a3 += upk(v0.w);
    }
  }
  if (ok) {
    uint4v pv;
    pv.x = packf(a0);
    pv.y = packf(a1);
    pv.z = packf(a2);
    pv.w = packf(a3);
    *(uint4v*)(Snp + (size_t)node * 320 + set * 160 + c4) = pv;
  }
}

// ---------------- fused GRU GEMM — R19: paired-kt supersteps ------------------
// Last untested axis: barriers per unit work. R16's 2100 cyc/block-kt wall =
// ~900 cyc pipe work + ~1200 cyc sync exposure at 2 barriers/kt. R19 processes
// TWO kts per barrier pair (both 16KB buffer sets live, 64KB LDS, 2 blocks/CU
// — occupancy 2 vs 4 proven perf-neutral in R13/R16). 16 barriers vs 30.
// Per superstep (k0=2S even, k1=k0+1):
//   read frags(k0,buf0)+frags(k1,buf1) -> lgkm(0)+barrier   (WAR safe)
//   stage(k0+2->buf0)+stage(k1+2->buf1)                     (issue early)
//   MFMA(k0); MFMA(k1)   (~1400 cyc matrix to hide stage latency)
//   vmcnt(0)+barrier                                        (RAW safe)
// MFMA order identical to sequential kts -> bit-identical output.

template<int KT>
__device__ __forceinline__ void stage_fn(
    const u32* __restrict__ Snp, const u32* __restrict__ npkc,
    const u16* __restrict__ Bhp, const u16* __restrict__ Blp,
    char* Ab, char* Bb, int tid, int w, int r0, int ccb) {
  // A tile: 128 rows x 32 k-cols packed u32 = 128B/row, XOR-swizzled chunks
  #pragma unroll
  for (int i = 0; i < 4; i++) {
    int cl = i * 256 + tid;                     // [0,1024)
    int row = cl >> 3;
    int q = (cl & 7) ^ (row & 7);
    int rg = min(r0 + row, NN - 1);
    if constexpr (KT < 10)
      async16(Snp + (size_t)rg * 320 + KT * 32 + q * 4, Ab + i * 4096 + w * 1024);
    else
      async16(npkc + (size_t)rg * 160 + (KT - 10) * 32 + q * 4, Ab + i * 4096 + w * 1024);
  }
  constexpr int koffB = (KT < 10) ? KT * 32 : 320 + (KT - 10) * 32;
  constexpr int skipg = (KT < 10) ? 3 : 2;      // zero-gate rows (exact skip)
  #pragma unroll
  for (int i = 0; i < 2; i++) {
    int cl = i * 256 + tid;                     // [0,512)
    int row = cl >> 2;
    int q = (cl & 3) ^ ((row >> 1) & 3);
    if (((row >> 4) & 3) != skipg) {            // wave-uniform predicate
      size_t gb = (size_t)(ccb * 128 + row) * KB + koffB + q * 8;
      int lb = i * 4096 + w * 1024;
      async16(Bhp + gb, Bb + lb);
      async16(Blp + gb, Bb + 8192 + lb);
    }
  }
}

template<int KTn>
__device__ __forceinline__ void read_frags_fn(
    const char* Ab, const char* Bb, int m, int quad, int mrow0, int nco0,
    uint4v (&A0)[4], uint4v (&A1)[4], short8 (&RBh)[3], short8 (&RBl)[3]) {
  #pragma unroll
  for (int jj = 0; jj < 3; jj++) {
    const int jsel = (jj == 2) ? ((KTn < 10) ? 2 : 3) : jj;
    int br = nco0 + jsel * 16 + m;
    int bd = br * 64 + ((quad ^ ((br >> 1) & 3)) * 16);
    RBh[jj] = *(const short8*)(Bb + bd);
    RBl[jj] = *(const short8*)(Bb + 8192 + bd);
  }
  #pragma unroll
  for (int mt = 0; mt < 4; mt++) {
    int r = mrow0 + mt * 16 + m;
    A0[mt] = *(const uint4v*)(Ab + r * 128 + (((2 * quad) ^ (r & 7)) * 16));
    A1[mt] = *(const uint4v*)(Ab + r * 128 + (((2 * quad + 1) ^ (r & 7)) * 16));
  }
}

template<int KT>
__device__ __forceinline__ void mfma_fn(
    const uint4v (&A0)[4], const uint4v (&A1)[4],
    const short8 (&MBh)[3], const short8 (&MBl)[3], float4v (&acc)[4][4]) {
  #pragma unroll
  for (int mt = 0; mt < 4; mt++) {
    u32 uu[8] = {A0[mt].x, A0[mt].y, A0[mt].z, A0[mt].w,
                 A1[mt].x, A1[mt].y, A1[mt].z, A1[mt].w};
    short8 ah, al;
    #pragma unroll
    for (int e2 = 0; e2 < 8; e2++) {
      ah[e2] = (short)(uu[e2] & 0xffffu);
      al[e2] = (short)(uu[e2] >> 16);
    }
    #pragma unroll
    for (int jj = 0; jj < 3; jj++) {
      const int J = (KT < 10) ? jj : ((jj == 2) ? 3 : jj);
      acc[mt][J] = __builtin_amdgcn_mfma_f32_16x16x32_bf16(ah, MBh[jj], acc[mt][J], 0, 0, 0);
      acc[mt][J] = __builtin_amdgcn_mfma_f32_16x16x32_bf16(ah, MBl[jj], acc[mt][J], 0, 0, 0);
      acc[mt][J] = __builtin_amdgcn_mfma_f32_16x16x32_bf16(al, MBh[jj], acc[mt][J], 0, 0, 0);
    }
  }
}

// superstep K0 (even): compute kts K0, K0+1; prefetch kts K0+2, K0+3
template<int K0>
__device__ __forceinline__ void gemm_superstep(
    const u32* __restrict__ Snp, const u32* __restrict__ npkc,
    const u16* __restrict__ Bhp, const u16* __restrict__ Blp,
    char (&Abuf)[2][16384], char (&Bbuf)[2][16384],
    int tid, int w, int m, int quad, int mrow0, int nco0, int r0, int ccb,
    float4v (&acc)[4][4]) {
  constexpr int K1 = K0 + 1;
  uint4v A0a[4], A1a[4], A0b[4], A1b[4];
  short8 FBha[3], FBla[3], FBhb[3], FBlb[3];
  // 1. read frags for both kts (28 ds_read in flight)
  read_frags_fn<K0>(Abuf[0], Bbuf[0], m, quad, mrow0, nco0, A0a, A1a, FBha, FBla);
  if constexpr (K1 <= 14)
    read_frags_fn<K1>(Abuf[1], Bbuf[1], m, quad, mrow0, nco0, A0b, A1b, FBhb, FBlb);
  asm volatile("s_waitcnt lgkmcnt(0)" ::: "memory");
  __builtin_amdgcn_sched_barrier(0);
  // 2. barrier + stage next pair into the now-free buffers
  if constexpr (K0 + 2 <= 14) {
    __builtin_amdgcn_s_barrier();               // all waves done reading
    stage_fn<K0 + 2>(Snp, npkc, Bhp, Blp, Abuf[0], Bbuf[0], tid, w, r0, ccb);
    if constexpr (K1 + 2 <= 14)
      stage_fn<K1 + 2>(Snp, npkc, Bhp, Blp, Abuf[1], Bbuf[1], tid, w, r0, ccb);
    __builtin_amdgcn_sched_barrier(0);
  }
  // 3. MFMA both kts (matrix pipe covers stage latency)
  __builtin_amdgcn_s_setprio(1);
  mfma_fn<K0>(A0a, A1a, FBha, FBla, acc);
  if constexpr (K1 <= 14)
    mfma_fn<K1>(A0b, A1b, FBhb, FBlb, acc);
  __builtin_amdgcn_s_setprio(0);
  __builtin_amdgcn_sched_barrier(0);
  // 4. staged pair complete before next superstep's reads
  if constexpr (K0 + 2 <= 14) {
    asm volatile("s_waitcnt vmcnt(0)" ::: "memory");
    __builtin_amdgcn_sched_barrier(0);
    __builtin_amdgcn_s_barrier();
  }
}

__global__ __launch_bounds__(256, 2) void gru_gemm_kernel(
    const u32* __restrict__ Snp, const u32* __restrict__ npkc,
    const u16* __restrict__ Bhp, const u16* __restrict__ Blp,
    const float* __restrict__ coefs, const int* __restrict__ rowptr,
    u32* __restrict__ npkn) {
  __shared__ char Abuf[2][16384];  // buf[kt&1]: 128 rows x 128B packed, XOR swizzle
  __shared__ char Bbuf[2][16384];  // [0,8K)=hi, [8K,16K)=lo
  const int bid = blockIdx.x;
  const int xcd = bid & 7;
  const int rest = bid >> 3;
  const int ccb = rest % 5;
  const int r0b = (rest / 5) * 8 + xcd;
  if (r0b >= NRB) return;
  const int r0 = r0b * 128;
  const int tid = threadIdx.x;
  const int w = tid >> 6, l = tid & 63;
  const int m = l & 15, quad = l >> 4;
  const int mrow0 = (w & 1) * 64;
  const int nco0 = (w >> 1) * 64;

  float4v acc[4][4];
  #pragma unroll
  for (int mt = 0; mt < 4; mt++)
    #pragma unroll
    for (int j = 0; j < 4; j++) acc[mt][j] = (float4v){0.f, 0.f, 0.f, 0.f};

  // ---- prologue: stage kts 0,1; drain; barrier ----
  stage_fn<0>(Snp, npkc, Bhp, Blp, Abuf[0], Bbuf[0], tid, w, r0, ccb);
  stage_fn<1>(Snp, npkc, Bhp, Blp, Abuf[1], Bbuf[1], tid, w, r0, ccb);
  asm volatile("s_waitcnt vmcnt(0)" ::: "memory");
  __builtin_amdgcn_sched_barrier(0);
  __builtin_amdgcn_s_barrier();

  // ---- 8 supersteps: (0,1),(2,3),...,(12,13),(14) ----
  #define SSTEP(K) gemm_superstep<K>(Snp, npkc, Bhp, Blp, Abuf, Bbuf, tid, w, m, \
                                     quad, mrow0, nco0, r0, ccb, acc)
  SSTEP(0); SSTEP(2); SSTEP(4); SSTEP(6);
  SSTEP(8); SSTEP(10); SSTEP(12); SSTEP(14);
  #undef SSTEP

  // ---- epilogue: wave handles c-chunk cc = ccb*2 + (w>>1); tile j = gate ----
  int c = (ccb * 2 + (w >> 1)) * 16 + m;
  if (c >= H) return;
  float u0r = coefs[c],            u0z = coefs[160 + c],
        u0n = coefs[320 + c];
  float u1r = coefs[VC + c],       u1z = coefs[VC + 160 + c],
        u1n = coefs[VC + 320 + c];
  float bsr = coefs[2 * VC + c],   bsz = coefs[2 * VC + 160 + c],
        bsn = coefs[2 * VC + 320 + c], bsh = coefs[2 * VC + 480 + c];
  #pragma unroll
  for (int mt = 0; mt < 4; mt++) {
    #pragma unroll
    for (int i = 0; i < 4; i++) {
      int row = r0 + mrow0 + mt * 16 + quad * 4 + i;
      if (row >= NN) continue;
      float d0 = (float)(rowptr[2 * row + 1] - rowptr[2 * row]);
      float d1 = (float)(rowptr[2 * row + 2] - rowptr[2 * row + 1]);
      float pr = acc[mt][0][i] + d0 * u0r + d1 * u1r + bsr;
      float pz = acc[mt][1][i] + d0 * u0z + d1 * u1z + bsz;
      float pn = acc[mt][2][i] + d0 * u0n + d1 * u1n + bsn;
      float ph = acc[mt][3][i] + bsh;
      float r_g = 1.f / (1.f + __expf(-pr));
      float z_g = 1.f / (1.f + __expf(-pz));
      float narg = pn + r_g * ph;
      float e2 = __expf(2.f * narg);
      float n_g = 1.f - 2.f / (e2 + 1.f);       // tanh, inf-safe
      float h = upk(npkc[(size_t)row * 160 + c]);
      npkn[(size_t)row * 160 + c] = packf((1.f - z_g) * n_g + z_g * h);
    }
  }
}

// ---------------- readout ----------------
__global__ __launch_bounds__(192) void segsum_kernel(const u32* __restrict__ npk,
                                                     const int* __restrict__ gstart,
                                                     float* __restrict__ gsum) {
  int g = blockIdx.x, chunk = blockIdx.y;
  int c = threadIdx.x;
  if (c >= H) return;
  int s = gstart[g], e = gstart[g + 1];
  int len = e - s;
  if (len <= 0) return;
  int per = (len + 3) / 4;
  int rs = s + chunk * per;
  int re = min(e, rs + per);
  if (rs >= re) return;
  float acc = 0.f;
  for (int r = rs; r < re; r++) acc += upk(npk[(size_t)r * 160 + c]);
  atomicAdd(&gsum[g * H + c], acc);
}

// one block per graph row; 192 thr. LDS: x[151], x1[80], x2[80].
__global__ __launch_bounds__(192) void head_kernel(
    const float* __restrict__ gsum, const float* __restrict__ pt,
    const float* __restrict__ fc1_w, const float* __restrict__ fc1_b,
    const float* __restrict__ fc2_w, const float* __restrict__ fc2_b,
    const float* __restrict__ fcL_w, const float* __restrict__ fcL_b,
    float* __restrict__ out) {
  __shared__ float x[151];
  __shared__ float x1[80];
  __shared__ float x2[80];
  int row = blockIdx.x;
  int t = threadIdx.x;
  if (t < 151) {
    float v;
    if (t < H) { float g = gsum[row * H + t]; v = (g > 1.f) ? logf(g) : 0.f; }
    else v = pt[row];
    x[t] = v;
  }
  __syncthreads();
  if (t < 80) {
    float acc = fc1_b[t];
    const float* wrow = fc1_w + t * 151;
    #pragma unroll 4
    for (int k = 0; k < 151; k++) acc += x[k] * wrow[k];
    x1[t] = (acc > 0.f) ? acc : 0.01f * acc;
  }
  __syncthreads();
  if (t < 80) {
    float acc = fc2_b[t];
    const float* wrow = fc2_w + t * 80;
    #pragma unroll 4
    for (int k = 0; k < 80; k++) acc += x1[k] * wrow[k];
    x2[t] = (acc > 0.f) ? acc : 0.01f * acc;
  }
  __syncthreads();
  if (t < 10) {
    float acc = fcL_b[t];
    const float* wrow = fcL_w + t * 80;
    #pragma unroll 4
    for (int k = 0; k < 80; k++) acc += x2[k] * wrow[k];
    out[row * 10 + t] = acc;
  }
}

extern "C" void kernel_launch(void* const* d_in, const int* in_sizes, int n_in,
                              void* d_out, int out_size, void* d_ws, size_t ws_size,
                              hipStream_t stream) {
  const float* nodes_in = (const float*)d_in[0];
  const float* problem_type = (const float*)d_in[1];
  const float* edge_W = (const float*)d_in[2];
  const float* edge_b = (const float*)d_in[3];
  const float* w_ih = (const float*)d_in[4];
  const float* w_hh = (const float*)d_in[5];
  const float* b_ih = (const float*)d_in[6];
  const float* b_hh = (const float*)d_in[7];
  const float* fc1_w = (const float*)d_in[8];
  const float* fc1_b = (const float*)d_in[9];
  const float* fc2_w = (const float*)d_in[10];
  const float* fc2_b = (const float*)d_in[11];
  const float* fcL_w = (const float*)d_in[12];
  const float* fcL_b = (const float*)d_in[13];
  const int* edges = (const int*)d_in[14];
  const int* graph_ids = (const int*)d_in[15];

  char* ws = (char*)d_ws;
  size_t off = 0;
  auto alloc = [&](size_t bytes) -> void* {
    void* p = ws + off;
    off = (off + bytes + 255) & ~(size_t)255;
    return p;
  };
  u32* npkA     = (u32*)alloc((size_t)NN * 160 * 4);           // 32 MB
  u32* npkB     = (u32*)alloc((size_t)NN * 160 * 4);           // 32 MB
  u32* Snp      = (u32*)alloc((size_t)NN * 320 * 4);           // 64 MB packed S
  u16* Bh       = (u16*)alloc((size_t)VC * KB * 2);            // 0.61 MB
  u16* Bl       = (u16*)alloc((size_t)VC * KB * 2);            // 0.61 MB
  float* coefs  = (float*)alloc(3 * VC * 4);
  int* rowptr   = (int*)alloc((2 * NN + 1) * 4);
  int* cursor   = (int*)alloc(2 * NN * 4);
  u16* colbuf   = (u16*)alloc(2ull * NE * 2);                  // 1.6 MB
  int* bsum     = (int*)alloc(128 * 4);
  int* boff     = (int*)alloc(128 * 4);
  int* gstart   = (int*)alloc((NG + 1) * 4);
  float* gsum   = (float*)alloc((size_t)NG * H * 4);

  const int n2 = 2 * NN;                 // 100000 counters
  const int nb = (n2 + 1023) / 1024;     // 98 scan blocks

  // ---- one-time setup ----
  hipMemsetAsync(cursor, 0, n2 * 4, stream);
  hist_kernel<<<(2 * NE + 255) / 256, 256, 0, stream>>>(edges, cursor);
  scan1_kernel<<<nb, 1024, 0, stream>>>(cursor, rowptr, bsum, n2);
  scan2_kernel<<<1, 128, 0, stream>>>(bsum, boff, nb);
  scan3_kernel<<<(n2 + 255) / 256, 256, 0, stream>>>(rowptr, boff, n2);
  total_kernel<<<1, 64, 0, stream>>>(rowptr, boff, n2, nb);
  copy_int_kernel<<<(n2 + 255) / 256, 256, 0, stream>>>(rowptr, cursor, n2);
  fill_kernel<<<(2 * NE + 255) / 256, 256, 0, stream>>>(edges, cursor, colbuf);
  bounds_kernel<<<1, 128, 0, stream>>>(graph_ids, gstart);
  build_B_kernel<<<(VC * KB + 255) / 256, 256, 0, stream>>>(w_ih, w_hh, edge_W, Bh, Bl);
  build_coef_kernel<<<(VC + 255) / 256, 256, 0, stream>>>(w_ih, edge_b, b_ih, b_hh, coefs);
  init_nodes_kernel<<<(NN * 160 + 255) / 256, 256, 0, stream>>>(nodes_in, npkA, npkB);
  pad_S_kernel<<<(NN * 20 + 255) / 256, 256, 0, stream>>>(Snp);

  // ---- 5 message-passing iterations (packed nodes ping-pong) ----
  const int ngrp = (NRB + 7) / 8;        // 49 groups of 8 row-blocks
  u32* nbuf[2] = {npkA, npkB};
  for (int pass = 0; pass < NPASS; pass++) {
    u32* cur = nbuf[pass & 1];
    u32* nxt = nbuf[1 - (pass & 1)];
    gather_kernel<<<(2 * NN * 64 + 255) / 256, 256, 0, stream>>>(cur, rowptr, colbuf, Snp);
    gru_gemm_kernel<<<ngrp * 5 * 8, 256, 0, stream>>>(
        Snp, cur, Bh, Bl, coefs, rowptr, nxt);
  }
  u32* fin = nbuf[NPASS & 1];

  // ---- readout ----
  hipMemsetAsync(gsum, 0, (size_t)NG * H * 4, stream);
  segsum_kernel<<<dim3(NG, 4), 192, 0, stream>>>(fin, gstart, gsum);
  head_kernel<<<NG, 192, 0, stream>>>(gsum, problem_type, fc1_w, fc1_b, fc2_w, fc2_b,
                                      fcL_w, fcL_b, (float*)d_out);
}

// Round 10
// 1094.177 us; speedup vs baseline: 1.1456x; 1.0146x over previous
//
#include <hip/hip_runtime.h>
#include <stdint.h>

#define NN 50000
#define H 150
#define NE 400000
#define NG 64
#define NPASS 5
#define KB 480          // GRU GEMM K: [S0(160) | S1(160) | nodes(160)]
#define VC 640          // 40 col-tiles: v = cc*64 + g*16 + cl, c = cc*16+cl
#define NRB 391         // row blocks of 128

typedef unsigned short u16;
typedef unsigned int u32;
typedef __attribute__((ext_vector_type(8))) short short8;
typedef __attribute__((ext_vector_type(4))) float float4v;
typedef __attribute__((ext_vector_type(4))) u32 uint4v;

// ---------------- helpers ----------------
__device__ __forceinline__ u16 f2bf_rn(float x) {
  union { float f; u32 u; } v; v.f = x;
  u32 r = v.u + 0x7fffu + ((v.u >> 16) & 1u);
  return (u16)(r >> 16);
}
__device__ __forceinline__ float bf2f(u16 h) {
  union { u32 u; float f; } v; v.u = ((u32)h) << 16;
  return v.f;
}
// packed word: low16 = hi bf16, high16 = lo bf16; value = hi + lo
__device__ __forceinline__ u32 packf(float v) {
  u16 hi = f2bf_rn(v);
  u16 lo = f2bf_rn(v - bf2f(hi));
  return (u32)hi | ((u32)lo << 16);
}
__device__ __forceinline__ float upk(u32 u) {
  union { u32 u; float f; } a, b;
  a.u = u << 16; b.u = u & 0xffff0000u;
  return a.f + b.f;
}
// async global->LDS, 16B per lane; lds dest must be wave-uniform base
__device__ __forceinline__ void async16(const void* g, void* l) {
  __builtin_amdgcn_global_load_lds(
      (const __attribute__((address_space(1))) unsigned int*)(uintptr_t)g,
      (__attribute__((address_space(3))) unsigned int*)(uint32_t)(uintptr_t)l,
      16, 0, 0);
}

// ---------------- CSR build (key = node*2 + set) ----------------
__global__ void hist_kernel(const int* __restrict__ edges, int* __restrict__ cnt) {
  int id = blockIdx.x * 256 + threadIdx.x;
  if (id >= 2 * NE) return;
  int dst = edges[id * 2];
  int set = id / NE;
  atomicAdd(&cnt[dst * 2 + set], 1);
}

__global__ __launch_bounds__(1024) void scan1_kernel(const int* __restrict__ cnt,
                                                     int* __restrict__ rowptr,
                                                     int* __restrict__ bsum, int n) {
  __shared__ int sd[1024];
  int t = threadIdx.x;
  int idx = blockIdx.x * 1024 + t;
  int v = (idx < n) ? cnt[idx] : 0;
  sd[t] = v;
  __syncthreads();
  for (int off = 1; off < 1024; off <<= 1) {
    int add = (t >= off) ? sd[t - off] : 0;
    __syncthreads();
    sd[t] += add;
    __syncthreads();
  }
  if (idx < n) rowptr[idx] = sd[t] - v;     // block-local exclusive
  if (t == 1023) bsum[blockIdx.x] = sd[1023];
}

__global__ __launch_bounds__(128) void scan2_kernel(const int* __restrict__ bsum,
                                                    int* __restrict__ boff, int nb) {
  __shared__ int sd[128];
  int t = threadIdx.x;
  int v = (t < nb) ? bsum[t] : 0;
  sd[t] = v;
  __syncthreads();
  for (int off = 1; off < 128; off <<= 1) {
    int add = (t >= off) ? sd[t - off] : 0;
    __syncthreads();
    sd[t] += add;
    __syncthreads();
  }
  boff[t] = sd[t] - v;                       // exclusive; boff[nb] = total
}

// R20: scan3 + total merged (one fewer dispatch)
__global__ void scan3_kernel(int* __restrict__ rowptr, const int* __restrict__ boff,
                             int n, int nb) {
  int idx = blockIdx.x * 256 + threadIdx.x;
  if (idx < n) rowptr[idx] += boff[idx >> 10];
  if (idx == 0) rowptr[n] = boff[nb];
}

__global__ void copy_int_kernel(const int* __restrict__ a, int* __restrict__ b, int n) {
  int id = blockIdx.x * 256 + threadIdx.x;
  if (id < n) b[id] = a[id];
}

__global__ void fill_kernel(const int* __restrict__ edges, int* __restrict__ cursor,
                            u16* __restrict__ colbuf) {
  int id = blockIdx.x * 256 + threadIdx.x;
  if (id >= 2 * NE) return;
  int dst = edges[id * 2];
  int src = edges[id * 2 + 1];
  int set = id / NE;
  int pos = atomicAdd(&cursor[dst * 2 + set], 1);
  colbuf[pos] = (u16)src;
}

__global__ void bounds_kernel(const int* __restrict__ gids, int* __restrict__ gstart) {
  int g = threadIdx.x;
  if (g > NG) return;
  int lo = 0, hi = NN;
  while (lo < hi) { int m = (lo + hi) >> 1; if (gids[m] < g) lo = m + 1; else hi = m; }
  gstart[g] = lo;
}

// ---------------- one-time weight prep ----------------
// B'[v][k], v in [0,640): g=(v>>4)&3, c=(v>>6)*16+(v&15)
// k<160: (W_ihg @ W0)[c][k]      (g<3; g3=0)
// 160<=k<320: (W_ihg @ W1)[c][k-160]
// 320<=k<480: g0: w_hh[c][kk], g1: w_hh[150+c][kk], g3: w_hh[300+c][kk], g2: 0
__global__ void build_B_kernel(const float* __restrict__ wih, const float* __restrict__ whh,
                               const float* __restrict__ eW,
                               u16* __restrict__ Bh, u16* __restrict__ Bl) {
  int id = blockIdx.x * 256 + threadIdx.x;
  if (id >= VC * KB) return;
  int v = id / KB, k = id % KB;
  int g = (v >> 4) & 3, c = (v >> 6) * 16 + (v & 15);
  int seg = k / 160, kk = k % 160;
  float val = 0.f;
  if (c < H && kk < H) {
    if (seg < 2) {
      if (g < 3) {
        const float* wr = wih + (size_t)(g * H + c) * H;
        const float* wc = eW + (size_t)seg * H * H + kk;
        float acc = 0.f;
        for (int t = 0; t < H; t++) acc += wr[t] * wc[(size_t)t * H];
        val = acc;
      }
    } else {
      if (g == 0) val = whh[(size_t)c * H + kk];
      else if (g == 1) val = whh[(size_t)(H + c) * H + kk];
      else if (g == 3) val = whh[(size_t)(2 * H + c) * H + kk];
    }
  }
  u16 h = f2bf_rn(val);
  Bh[id] = h;
  Bl[id] = f2bf_rn(val - bf2f(h));
}

// coefs[0][g*160+c] = W_ihg @ b0 (deg0 coef), coefs[1] = W_ihg @ b1, coefs[2] = gate bias
__global__ void build_coef_kernel(const float* __restrict__ wih,
                                  const float* __restrict__ eb,
                                  const float* __restrict__ bih, const float* __restrict__ bhh,
                                  float* __restrict__ coefs) {
  int id = threadIdx.x + blockIdx.x * 256;
  if (id >= VC) return;
  int g = id / 160, c = id % 160;
  float u0 = 0.f, u1 = 0.f, bs = 0.f;
  if (c < H) {
    if (g < 3) {
      const float* wr = wih + (size_t)(g * H + c) * H;
      for (int t = 0; t < H; t++) { u0 += wr[t] * eb[t]; u1 += wr[t] * eb[H + t]; }
    }
    if (g == 0) bs = bih[c] + bhh[c];
    else if (g == 1) bs = bih[H + c] + bhh[H + c];
    else if (g == 2) bs = bih[2 * H + c];
    else bs = bhh[2 * H + c];
  }
  coefs[id] = u0;
  coefs[VC + id] = u1;
  coefs[2 * VC + id] = bs;
}

// pack input nodes into npkA; zero pad cols of both buffers.
// R20: uint4-vectorized — thread handles 4 consecutive cols of one row.
__global__ void init_nodes_kernel(const float* __restrict__ nin,
                                  u32* __restrict__ npkA, u32* __restrict__ npkB) {
  int id = blockIdx.x * 256 + threadIdx.x;
  if (id >= NN * 40) return;
  int r = id / 40, q = id % 40;
  int c = q * 4;
  uint4v a;
  const float* src = nin + (size_t)r * H + c;
  u32 w0 = 0, w1 = 0, w2 = 0, w3 = 0;
  if (c + 3 < H) {
    w0 = packf(src[0]); w1 = packf(src[1]); w2 = packf(src[2]); w3 = packf(src[3]);
  } else {
    if (c < H) w0 = packf(src[0]);
    if (c + 1 < H) w1 = packf(src[1]);
    if (c + 2 < H) w2 = packf(src[2]);
    // c+3 >= H -> 0
  }
  a.x = w0; a.y = w1; a.z = w2; a.w = w3;
  *(uint4v*)(npkA + (size_t)r * 160 + c) = a;
  if (c >= 148) {   // cover pad cols 150..159 of npkB (and harmless 148/149 dup region)
    uint4v z = {0, 0, 0, 0};
    if (c >= 152) *(uint4v*)(npkB + (size_t)r * 160 + c) = z;
    else if (c == 148) { npkB[(size_t)r * 160 + 150] = 0; npkB[(size_t)r * 160 + 151] = 0; }
  }
}

// zero the pad columns of packed S (cols 150..159 per set); gather also writes
// them (sums of zero pad cols of npk) — same value, kept for first-pass safety
__global__ void pad_S_kernel(u32* __restrict__ Snp) {
  int id = blockIdx.x * 256 + threadIdx.x;
  if (id >= NN * 20) return;
  int r = id / 20, rem = id % 20;
  int set = rem / 10, t = rem % 10;
  Snp[(size_t)r * 320 + set * 160 + H + t] = 0;
}

// ---------------- gather: Snp[n][set*160+c] = packed sum of raw node rows ------
// R18 form (1 VMEM/edge): lane l<40 loads cols 4l..4l+3 as one uint4; lanes
// 40-63 masked. Adjacency list loaded coalesced + readlane broadcast; 4-edge
// unroll. Gather is at its cache-line traffic floor (R17/R18 A/B established
// lines, not instructions or bytes, set its rate). Bit-identical accumulation.
__global__ __launch_bounds__(256) void gather_kernel(
    const u32* __restrict__ npk, const int* __restrict__ rowptr,
    const u16* __restrict__ colbuf, u32* __restrict__ Snp) {
  int gtid = blockIdx.x * 256 + threadIdx.x;
  int wid = gtid >> 6;
  if (wid >= 2 * NN) return;
  int node = wid >> 1, set = wid & 1;
  int lane = gtid & 63;
  int s = rowptr[2 * node + set], e = rowptr[2 * node + set + 1];
  int deg = e - s;
  int c4 = 4 * lane;
  bool ok = (lane < 40);               // cols 0..159 in 40 lanes
  float a0 = 0.f, a1 = 0.f, a2 = 0.f, a3 = 0.f;
  for (int base = 0; base < deg; base += 64) {
    int rem = min(64, deg - base);
    u32 srcv = 0;
    if (lane < rem) srcv = (u32)colbuf[s + base + lane];
    int i = 0;
    for (; i + 3 < rem; i += 4) {
      int r0 = __builtin_amdgcn_readlane((int)srcv, i);
      int r1 = __builtin_amdgcn_readlane((int)srcv, i + 1);
      int r2 = __builtin_amdgcn_readlane((int)srcv, i + 2);
      int r3 = __builtin_amdgcn_readlane((int)srcv, i + 3);
      uint4v v0 = {0, 0, 0, 0}, v1 = {0, 0, 0, 0};
      uint4v v2 = {0, 0, 0, 0}, v3 = {0, 0, 0, 0};
      if (ok) {
        v0 = *(const uint4v*)(npk + (size_t)(u32)r0 * 160 + c4);
        v1 = *(const uint4v*)(npk + (size_t)(u32)r1 * 160 + c4);
        v2 = *(const uint4v*)(npk + (size_t)(u32)r2 * 160 + c4);
        v3 = *(const uint4v*)(npk + (size_t)(u32)r3 * 160 + c4);
      }
      a0 += upk(v0.x) + upk(v1.x);
      a1 += upk(v0.y) + upk(v1.y);
      a2 += upk(v0.z) + upk(v1.z);
      a3 += upk(v0.w) + upk(v1.w);
      a0 += upk(v2.x) + upk(v3.x);
      a1 += upk(v2.y) + upk(v3.y);
      a2 += upk(v2.z) + upk(v3.z);
      a3 += upk(v2.w) + upk(v3.w);
    }
    for (; i + 1 < rem; i += 2) {
      int r0 = __builtin_amdgcn_readlane((int)srcv, i);
      int r1 = __builtin_amdgcn_readlane((int)srcv, i + 1);
      uint4v v0 = {0, 0, 0, 0}, v1 = {0, 0, 0, 0};
      if (ok) {
        v0 = *(const uint4v*)(npk + (size_t)(u32)r0 * 160 + c4);
        v1 = *(const uint4v*)(npk + (size_t)(u32)r1 * 160 + c4);
      }
      a0 += upk(v0.x) + upk(v1.x);
      a1 += upk(v0.y) + upk(v1.y);
      a2 += upk(v0.z) + upk(v1.z);
      a3 += upk(v0.w) + upk(v1.w);
    }
    if (i < rem) {
      int r0 = __builtin_amdgcn_readlane((int)srcv, i);
      uint4v v0 = {0, 0, 0, 0};
      if (ok) v0 = *(const uint4v*)(npk + (size_t)(u32)r0 * 160 + c4);
      a0 += upk(v0.x);
      a1 += upk(v0.y);
      a2 += upk(v0.z);
      a3 += upk(v0.w);
    }
  }
  if (ok) {
    uint4v pv;
    pv.x = packf(a0);
    pv.y = packf(a1);
    pv.z = packf(a2);
    pv.w = packf(a3);
    *(uint4v*)(Snp + (size_t)node * 320 + set * 160 + c4) = pv;
  }
}

// ---------------- fused GRU GEMM — R19 verbatim: paired-kt supersteps ---------
// 2 kts per barrier pair (both 16KB buffer sets live, 64KB LDS, 2 blocks/CU).
// 16 barriers vs 30; HBM writes halved vs single-buffer. Best total (1110).

template<int KT>
__device__ __forceinline__ void stage_fn(
    const u32* __restrict__ Snp, const u32* __restrict__ npkc,
    const u16* __restrict__ Bhp, const u16* __restrict__ Blp,
    char* Ab, char* Bb, int tid, int w, int r0, int ccb) {
  // A tile: 128 rows x 32 k-cols packed u32 = 128B/row, XOR-swizzled chunks
  #pragma unroll
  for (int i = 0; i < 4; i++) {
    int cl = i * 256 + tid;                     // [0,1024)
    int row = cl >> 3;
    int q = (cl & 7) ^ (row & 7);
    int rg = min(r0 + row, NN - 1);
    if constexpr (KT < 10)
      async16(Snp + (size_t)rg * 320 + KT * 32 + q * 4, Ab + i * 4096 + w * 1024);
    else
      async16(npkc + (size_t)rg * 160 + (KT - 10) * 32 + q * 4, Ab + i * 4096 + w * 1024);
  }
  constexpr int koffB = (KT < 10) ? KT * 32 : 320 + (KT - 10) * 32;
  constexpr int skipg = (KT < 10) ? 3 : 2;      // zero-gate rows (exact skip)
  #pragma unroll
  for (int i = 0; i < 2; i++) {
    int cl = i * 256 + tid;                     // [0,512)
    int row = cl >> 2;
    int q = (cl & 3) ^ ((row >> 1) & 3);
    if (((row >> 4) & 3) != skipg) {            // wave-uniform predicate
      size_t gb = (size_t)(ccb * 128 + row) * KB + koffB + q * 8;
      int lb = i * 4096 + w * 1024;
      async16(Bhp + gb, Bb + lb);
      async16(Blp + gb, Bb + 8192 + lb);
    }
  }
}

template<int KTn>
__device__ __forceinline__ void read_frags_fn(
    const char* Ab, const char* Bb, int m, int quad, int mrow0, int nco0,
    uint4v (&A0)[4], uint4v (&A1)[4], short8 (&RBh)[3], short8 (&RBl)[3]) {
  #pragma unroll
  for (int jj = 0; jj < 3; jj++) {
    const int jsel = (jj == 2) ? ((KTn < 10) ? 2 : 3) : jj;
    int br = nco0 + jsel * 16 + m;
    int bd = br * 64 + ((quad ^ ((br >> 1) & 3)) * 16);
    RBh[jj] = *(const short8*)(Bb + bd);
    RBl[jj] = *(const short8*)(Bb + 8192 + bd);
  }
  #pragma unroll
  for (int mt = 0; mt < 4; mt++) {
    int r = mrow0 + mt * 16 + m;
    A0[mt] = *(const uint4v*)(Ab + r * 128 + (((2 * quad) ^ (r & 7)) * 16));
    A1[mt] = *(const uint4v*)(Ab + r * 128 + (((2 * quad + 1) ^ (r & 7)) * 16));
  }
}

template<int KT>
__device__ __forceinline__ void mfma_fn(
    const uint4v (&A0)[4], const uint4v (&A1)[4],
    const short8 (&MBh)[3], const short8 (&MBl)[3], float4v (&acc)[4][4]) {
  #pragma unroll
  for (int mt = 0; mt < 4; mt++) {
    u32 uu[8] = {A0[mt].x, A0[mt].y, A0[mt].z, A0[mt].w,
                 A1[mt].x, A1[mt].y, A1[mt].z, A1[mt].w};
    short8 ah, al;
    #pragma unroll
    for (int e2 = 0; e2 < 8; e2++) {
      ah[e2] = (short)(uu[e2] & 0xffffu);
      al[e2] = (short)(uu[e2] >> 16);
    }
    #pragma unroll
    for (int jj = 0; jj < 3; jj++) {
      const int J = (KT < 10) ? jj : ((jj == 2) ? 3 : jj);
      acc[mt][J] = __builtin_amdgcn_mfma_f32_16x16x32_bf16(ah, MBh[jj], acc[mt][J], 0, 0, 0);
      acc[mt][J] = __builtin_amdgcn_mfma_f32_16x16x32_bf16(ah, MBl[jj], acc[mt][J], 0, 0, 0);
      acc[mt][J] = __builtin_amdgcn_mfma_f32_16x16x32_bf16(al, MBh[jj], acc[mt][J], 0, 0, 0);
    }
  }
}

// superstep K0 (even): compute kts K0, K0+1; prefetch kts K0+2, K0+3
template<int K0>
__device__ __forceinline__ void gemm_superstep(
    const u32* __restrict__ Snp, const u32* __restrict__ npkc,
    const u16* __restrict__ Bhp, const u16* __restrict__ Blp,
    char (&Abuf)[2][16384], char (&Bbuf)[2][16384],
    int tid, int w, int m, int quad, int mrow0, int nco0, int r0, int ccb,
    float4v (&acc)[4][4]) {
  constexpr int K1 = K0 + 1;
  uint4v A0a[4], A1a[4], A0b[4], A1b[4];
  short8 FBha[3], FBla[3], FBhb[3], FBlb[3];
  // 1. read frags for both kts (28 ds_read in flight)
  read_frags_fn<K0>(Abuf[0], Bbuf[0], m, quad, mrow0, nco0, A0a, A1a, FBha, FBla);
  if constexpr (K1 <= 14)
    read_frags_fn<K1>(Abuf[1], Bbuf[1], m, quad, mrow0, nco0, A0b, A1b, FBhb, FBlb);
  asm volatile("s_waitcnt lgkmcnt(0)" ::: "memory");
  __builtin_amdgcn_sched_barrier(0);
  // 2. barrier + stage next pair into the now-free buffers
  if constexpr (K0 + 2 <= 14) {
    __builtin_amdgcn_s_barrier();               // all waves done reading
    stage_fn<K0 + 2>(Snp, npkc, Bhp, Blp, Abuf[0], Bbuf[0], tid, w, r0, ccb);
    if constexpr (K1 + 2 <= 14)
      stage_fn<K1 + 2>(Snp, npkc, Bhp, Blp, Abuf[1], Bbuf[1], tid, w, r0, ccb);
    __builtin_amdgcn_sched_barrier(0);
  }
  // 3. MFMA both kts (matrix pipe covers stage latency)
  __builtin_amdgcn_s_setprio(1);
  mfma_fn<K0>(A0a, A1a, FBha, FBla, acc);
  if constexpr (K1 <= 14)
    mfma_fn<K1>(A0b, A1b, FBhb, FBlb, acc);
  __builtin_amdgcn_s_setprio(0);
  __builtin_amdgcn_sched_barrier(0);
  // 4. staged pair complete before next superstep's reads
  if constexpr (K0 + 2 <= 14) {
    asm volatile("s_waitcnt vmcnt(0)" ::: "memory");
    __builtin_amdgcn_sched_barrier(0);
    __builtin_amdgcn_s_barrier();
  }
}

__global__ __launch_bounds__(256, 2) void gru_gemm_kernel(
    const u32* __restrict__ Snp, const u32* __restrict__ npkc,
    const u16* __restrict__ Bhp, const u16* __restrict__ Blp,
    const float* __restrict__ coefs, const int* __restrict__ rowptr,
    u32* __restrict__ npkn) {
  __shared__ char Abuf[2][16384];  // buf[kt&1]: 128 rows x 128B packed, XOR swizzle
  __shared__ char Bbuf[2][16384];  // [0,8K)=hi, [8K,16K)=lo
  const int bid = blockIdx.x;
  const int xcd = bid & 7;
  const int rest = bid >> 3;
  const int ccb = rest % 5;
  const int r0b = (rest / 5) * 8 + xcd;
  if (r0b >= NRB) return;
  const int r0 = r0b * 128;
  const int tid = threadIdx.x;
  const int w = tid >> 6, l = tid & 63;
  const int m = l & 15, quad = l >> 4;
  const int mrow0 = (w & 1) * 64;
  const int nco0 = (w >> 1) * 64;

  float4v acc[4][4];
  #pragma unroll
  for (int mt = 0; mt < 4; mt++)
    #pragma unroll
    for (int j = 0; j < 4; j++) acc[mt][j] = (float4v){0.f, 0.f, 0.f, 0.f};

  // ---- prologue: stage kts 0,1; drain; barrier ----
  stage_fn<0>(Snp, npkc, Bhp, Blp, Abuf[0], Bbuf[0], tid, w, r0, ccb);
  stage_fn<1>(Snp, npkc, Bhp, Blp, Abuf[1], Bbuf[1], tid, w, r0, ccb);
  asm volatile("s_waitcnt vmcnt(0)" ::: "memory");
  __builtin_amdgcn_sched_barrier(0);
  __builtin_amdgcn_s_barrier();

  // ---- 8 supersteps: (0,1),(2,3),...,(12,13),(14) ----
  #define SSTEP(K) gemm_superstep<K>(Snp, npkc, Bhp, Blp, Abuf, Bbuf, tid, w, m, \
                                     quad, mrow0, nco0, r0, ccb, acc)
  SSTEP(0); SSTEP(2); SSTEP(4); SSTEP(6);
  SSTEP(8); SSTEP(10); SSTEP(12); SSTEP(14);
  #undef SSTEP

  // ---- epilogue: wave handles c-chunk cc = ccb*2 + (w>>1); tile j = gate ----
  int c = (ccb * 2 + (w >> 1)) * 16 + m;
  if (c >= H) return;
  float u0r = coefs[c],            u0z = coefs[160 + c],
        u0n = coefs[320 + c];
  float u1r = coefs[VC + c],       u1z = coefs[VC + 160 + c],
        u1n = coefs[VC + 320 + c];
  float bsr = coefs[2 * VC + c],   bsz = coefs[2 * VC + 160 + c],
        bsn = coefs[2 * VC + 320 + c], bsh = coefs[2 * VC + 480 + c];
  #pragma unroll
  for (int mt = 0; mt < 4; mt++) {
    #pragma unroll
    for (int i = 0; i < 4; i++) {
      int row = r0 + mrow0 + mt * 16 + quad * 4 + i;
      if (row >= NN) continue;
      float d0 = (float)(rowptr[2 * row + 1] - rowptr[2 * row]);
      float d1 = (float)(rowptr[2 * row + 2] - rowptr[2 * row + 1]);
      float pr = acc[mt][0][i] + d0 * u0r + d1 * u1r + bsr;
      float pz = acc[mt][1][i] + d0 * u0z + d1 * u1z + bsz;
      float pn = acc[mt][2][i] + d0 * u0n + d1 * u1n + bsn;
      float ph = acc[mt][3][i] + bsh;
      float r_g = 1.f / (1.f + __expf(-pr));
      float z_g = 1.f / (1.f + __expf(-pz));
      float narg = pn + r_g * ph;
      float e2 = __expf(2.f * narg);
      float n_g = 1.f - 2.f / (e2 + 1.f);       // tanh, inf-safe
      float h = upk(npkc[(size_t)row * 160 + c]);
      npkn[(size_t)row * 160 + c] = packf((1.f - z_g) * n_g + z_g * h);
    }
  }
}

// ---------------- readout ----------------
// R20: 16 row-chunks per graph (was 4) — 4x block parallelism, serial loop ~49.
__global__ __launch_bounds__(192) void segsum_kernel(const u32* __restrict__ npk,
                                                     const int* __restrict__ gstart,
                                                     float* __restrict__ gsum) {
  int g = blockIdx.x, chunk = blockIdx.y;
  int c = threadIdx.x;
  if (c >= H) return;
  int s = gstart[g], e = gstart[g + 1];
  int len = e - s;
  if (len <= 0) return;
  int per = (len + 15) / 16;
  int rs = s + chunk * per;
  int re = min(e, rs + per);
  if (rs >= re) return;
  float acc = 0.f;
  for (int r = rs; r < re; r++) acc += upk(npk[(size_t)r * 160 + c]);
  atomicAdd(&gsum[g * H + c], acc);
}

// one block per graph row; 192 thr. LDS: x[151], x1[80], x2[80].
__global__ __launch_bounds__(192) void head_kernel(
    const float* __restrict__ gsum, const float* __restrict__ pt,
    const float* __restrict__ fc1_w, const float* __restrict__ fc1_b,
    const float* __restrict__ fc2_w, const float* __restrict__ fc2_b,
    const float* __restrict__ fcL_w, const float* __restrict__ fcL_b,
    float* __restrict__ out) {
  __shared__ float x[151];
  __shared__ float x1[80];
  __shared__ float x2[80];
  int row = blockIdx.x;
  int t = threadIdx.x;
  if (t < 151) {
    float v;
    if (t < H) { float g = gsum[row * H + t]; v = (g > 1.f) ? logf(g) : 0.f; }
    else v = pt[row];
    x[t] = v;
  }
  __syncthreads();
  if (t < 80) {
    float acc = fc1_b[t];
    const float* wrow = fc1_w + t * 151;
    #pragma unroll 4
    for (int k = 0; k < 151; k++) acc += x[k] * wrow[k];
    x1[t] = (acc > 0.f) ? acc : 0.01f * acc;
  }
  __syncthreads();
  if (t < 80) {
    float acc = fc2_b[t];
    const float* wrow = fc2_w + t * 80;
    #pragma unroll 4
    for (int k = 0; k < 80; k++) acc += x1[k] * wrow[k];
    x2[t] = (acc > 0.f) ? acc : 0.01f * acc;
  }
  __syncthreads();
  if (t < 10) {
    float acc = fcL_b[t];
    const float* wrow = fcL_w + t * 80;
    #pragma unroll 4
    for (int k = 0; k < 80; k++) acc += x2[k] * wrow[k];
    out[row * 10 + t] = acc;
  }
}

extern "C" void kernel_launch(void* const* d_in, const int* in_sizes, int n_in,
                              void* d_out, int out_size, void* d_ws, size_t ws_size,
                              hipStream_t stream) {
  const float* nodes_in = (const float*)d_in[0];
  const float* problem_type = (const float*)d_in[1];
  const float* edge_W = (const float*)d_in[2];
  const float* edge_b = (const float*)d_in[3];
  const float* w_ih = (const float*)d_in[4];
  const float* w_hh = (const float*)d_in[5];
  const float* b_ih = (const float*)d_in[6];
  const float* b_hh = (const float*)d_in[7];
  const float* fc1_w = (const float*)d_in[8];
  const float* fc1_b = (const float*)d_in[9];
  const float* fc2_w = (const float*)d_in[10];
  const float* fc2_b = (const float*)d_in[11];
  const float* fcL_w = (const float*)d_in[12];
  const float* fcL_b = (const float*)d_in[13];
  const int* edges = (const int*)d_in[14];
  const int* graph_ids = (const int*)d_in[15];

  char* ws = (char*)d_ws;
  size_t off = 0;
  auto alloc = [&](size_t bytes) -> void* {
    void* p = ws + off;
    off = (off + bytes + 255) & ~(size_t)255;
    return p;
  };
  u32* npkA     = (u32*)alloc((size_t)NN * 160 * 4);           // 32 MB
  u32* npkB     = (u32*)alloc((size_t)NN * 160 * 4);           // 32 MB
  u32* Snp      = (u32*)alloc((size_t)NN * 320 * 4);           // 64 MB packed S
  u16* Bh       = (u16*)alloc((size_t)VC * KB * 2);            // 0.61 MB
  u16* Bl       = (u16*)alloc((size_t)VC * KB * 2);            // 0.61 MB
  float* coefs  = (float*)alloc(3 * VC * 4);
  int* rowptr   = (int*)alloc((2 * NN + 1) * 4);
  int* cursor   = (int*)alloc(2 * NN * 4);
  u16* colbuf   = (u16*)alloc(2ull * NE * 2);                  // 1.6 MB
  int* bsum     = (int*)alloc(128 * 4);
  int* boff     = (int*)alloc(128 * 4);
  int* gstart   = (int*)alloc((NG + 1) * 4);
  float* gsum   = (float*)alloc((size_t)NG * H * 4);

  const int n2 = 2 * NN;                 // 100000 counters
  const int nb = (n2 + 1023) / 1024;     // 98 scan blocks

  // ---- one-time setup ----
  hipMemsetAsync(cursor, 0, n2 * 4, stream);
  hist_kernel<<<(2 * NE + 255) / 256, 256, 0, stream>>>(edges, cursor);
  scan1_kernel<<<nb, 1024, 0, stream>>>(cursor, rowptr, bsum, n2);
  scan2_kernel<<<1, 128, 0, stream>>>(bsum, boff, nb);
  scan3_kernel<<<(n2 + 255) / 256, 256, 0, stream>>>(rowptr, boff, n2, nb);
  copy_int_kernel<<<(n2 + 255) / 256, 256, 0, stream>>>(rowptr, cursor, n2);
  fill_kernel<<<(2 * NE + 255) / 256, 256, 0, stream>>>(edges, cursor, colbuf);
  bounds_kernel<<<1, 128, 0, stream>>>(graph_ids, gstart);
  build_B_kernel<<<(VC * KB + 255) / 256, 256, 0, stream>>>(w_ih, w_hh, edge_W, Bh, Bl);
  build_coef_kernel<<<(VC + 255) / 256, 256, 0, stream>>>(w_ih, edge_b, b_ih, b_hh, coefs);
  init_nodes_kernel<<<(NN * 40 + 255) / 256, 256, 0, stream>>>(nodes_in, npkA, npkB);
  pad_S_kernel<<<(NN * 20 + 255) / 256, 256, 0, stream>>>(Snp);

  // ---- 5 message-passing iterations (packed nodes ping-pong) ----
  const int ngrp = (NRB + 7) / 8;        // 49 groups of 8 row-blocks
  u32* nbuf[2] = {npkA, npkB};
  for (int pass = 0; pass < NPASS; pass++) {
    u32* cur = nbuf[pass & 1];
    u32* nxt = nbuf[1 - (pass & 1)];
    gather_kernel<<<(2 * NN * 64 + 255) / 256, 256, 0, stream>>>(cur, rowptr, colbuf, Snp);
    gru_gemm_kernel<<<ngrp * 5 * 8, 256, 0, stream>>>(
        Snp, cur, Bh, Bl, coefs, rowptr, nxt);
  }
  u32* fin = nbuf[NPASS & 1];

  // ---- readout ----
  hipMemsetAsync(gsum, 0, (size_t)NG * H * 4, stream);
  segsum_kernel<<<dim3(NG, 16), 192, 0, stream>>>(fin, gstart, gsum);
  head_kernel<<<NG, 192, 0, stream>>>(gsum, problem_type, fc1_w, fc1_b, fc2_w, fc2_b,
                                      fcL_w, fcL_b, (float*)d_out);
}